// Round 1
// 598.667 us; speedup vs baseline: 1.6681x; 1.6681x over previous
//
#include <hip/hip_runtime.h>
#include <hip/hip_bf16.h>
#include <math.h>

// Round 5: remove LDS weight staging from edge_kernel. MFMA B-fragments are loaded
// directly from global (16B-aligned repadded bf16 weight table, L2-resident).
// Activation LDS buffers are lifetime-aliased: 155.6 KB -> 46.8 KB dynamic LDS
// => 3 blocks/CU (12 waves/CU) instead of 1 block/CU (4 waves/CU).

static __device__ __forceinline__ float siluf(float x) { return x / (1.f + __expf(-x)); }
static __device__ __forceinline__ float sspf(float x) {
  return fmaxf(x, 0.f) + log1pf(__expf(-fabsf(x))) - 0.6931471805599453f;
}
static __device__ __forceinline__ short f2b(float x) {
  __hip_bfloat16 b = __float2bfloat16(x);
  short s; __builtin_memcpy(&s, &b, 2); return s;
}
static __device__ __forceinline__ float b2f(short s) {
  unsigned int u = ((unsigned int)(unsigned short)s) << 16;
  float f; __builtin_memcpy(&f, &u, 4); return f;
}

typedef __attribute__((ext_vector_type(4))) short short4v;
typedef __attribute__((ext_vector_type(8))) short short8v;
typedef __attribute__((ext_vector_type(16))) float f32x16;

// LDS A-fragment load: two ds_read_b64 (strides chosen ≡ 4 mod 8 elems => 8B-aligned)
static __device__ __forceinline__ short8v ld8(const short* p) {
  const short4v* q = (const short4v*)p;
  short4v a = q[0], b = q[1];
  short8v r;
  r[0] = a[0]; r[1] = a[1]; r[2] = a[2]; r[3] = a[3];
  r[4] = b[0]; r[5] = b[1]; r[6] = b[2]; r[7] = b[3];
  return r;
}

// Global B-fragment load: single global_load_dwordx4 (all strides multiple of 8 elems
// and all base offsets multiple of 8 elems => every fragment address is 16B-aligned)
static __device__ __forceinline__ short8v gld8(const short* __restrict__ p) {
  return *reinterpret_cast<const short8v*>(p);
}

// ---- bf16 weight table in global ws (elem offsets), all [N][K_pad] transposed, K_pad % 8 == 0 ----
#define WOFF_FSW1 0        // fsW1T [64][200]
#define WOFF_FSW2 12800    // fsW2T [320][72]
#define WOFF_FEW1 35840    // feW1T [32][40]
#define WOFF_FEW2 37120    // feW2T [320][24]
#define WOFF_GW1  44800    // gW1T  [128][136]
#define WOFF_GW2  62208    // gW2T  [128][136]
#define WOFF_WO0  79616    // Wo0T  [64][72]
#define WOFF_WO1  84224    // Wo1T  [64][72]
#define W_TOTAL   88832

__global__ __launch_bounds__(256) void prep_weights(
    const float* __restrict__ fsW1, const float* __restrict__ fsW2,
    const float* __restrict__ feW1, const float* __restrict__ feW2,
    const float* __restrict__ gW1, const float* __restrict__ gW2,
    const float* __restrict__ Wo0, const float* __restrict__ Wo1,
    short* __restrict__ wsb)
{
  const int gt = blockIdx.x * blockDim.x + threadIdx.x;
  const int gs = gridDim.x * blockDim.x;
  for (int i = gt; i < 64 * 200; i += gs)  { int n = i / 200, k = i % 200; wsb[WOFF_FSW1 + i] = (k < 192) ? f2b(fsW1[k * 64 + n]) : 0; }
  for (int i = gt; i < 320 * 72; i += gs)  { int n = i / 72,  k = i % 72;  wsb[WOFF_FSW2 + i] = (k < 64)  ? f2b(fsW2[k * 320 + n]) : 0; }
  for (int i = gt; i < 32 * 40; i += gs)   { int n = i / 40,  k = i % 40;  wsb[WOFF_FEW1 + i] = (n < 8 && k < 32) ? f2b(feW1[k * 8 + n]) : 0; }
  for (int i = gt; i < 320 * 24; i += gs)  { int n = i / 24,  k = i % 24;  wsb[WOFF_FEW2 + i] = (k < 8)   ? f2b(feW2[k * 320 + n]) : 0; }
  for (int i = gt; i < 128 * 136; i += gs) { int n = i / 136, k = i % 136; wsb[WOFF_GW1 + i]  = (k < 128) ? f2b(gW1[k * 128 + n]) : 0; }
  for (int i = gt; i < 128 * 136; i += gs) { int n = i / 136, k = i % 136; wsb[WOFF_GW2 + i]  = (k < 128) ? f2b(gW2[k * 128 + n]) : 0; }
  for (int i = gt; i < 64 * 72; i += gs)   { int n = i / 72,  k = i % 72;  wsb[WOFF_WO0 + i]  = (k < 64)  ? f2b(Wo0[k * 64 + n]) : 0; }
  for (int i = gt; i < 64 * 72; i += gs)   { int n = i / 72,  k = i % 72;  wsb[WOFF_WO1 + i]  = (k < 64)  ? f2b(Wo1[k * 64 + n]) : 0; }
}

// ---------------- node kernel (unchanged) ----------------
__global__ __launch_bounds__(256) void node_kernel(
    const float* __restrict__ na,
    const float* __restrict__ Wi0, const float* __restrict__ bi0,
    const float* __restrict__ Wi1,
    const float* __restrict__ gpW1, const float* __restrict__ gpb1,
    const float* __restrict__ gpW2, const float* __restrict__ gpb2,
    const float* __restrict__ Wn0, const float* __restrict__ bn0,
    const float* __restrict__ Wn1,
    float* __restrict__ na0, float* __restrict__ h, int N)
{
  const int wave = threadIdx.x >> 6, lane = threadIdx.x & 63;
  int node = blockIdx.x * 4 + wave;
  const bool valid = node < N;
  if (node >= N) node = N - 1;
  __shared__ float lds[4][256 + 128 + 128 + 256];
  float* xrow = lds[wave];
  float* f0   = xrow + 256;
  float* t    = f0 + 128;
  float* row2 = t + 128;

  const float* xp = na + (size_t)node * 256;
  for (int i = lane; i < 256; i += 64) xrow[i] = xp[i];
  __syncthreads();
  {
    const int v = lane;
    float sa = 0.f, a0 = 0.f, a1 = 0.f, a2 = 0.f;
#pragma unroll 4
    for (int u = 0; u < 64; ++u) {
      const float w0 = Wi0[u * 64 + v];
      const float w1 = Wi1[u * 64 + v];
      sa += xrow[u] * w0;
      a0 += xrow[64 + 3 * u + 0] * w1;
      a1 += xrow[64 + 3 * u + 1] * w1;
      a2 += xrow[64 + 3 * u + 2] * w1;
    }
    if (valid) {
      float* op = na0 + (size_t)node * 256;
      op[v] = sa * 0.125f + bi0[v];
      op[64 + 3 * v + 0] = a0 * 0.125f;
      op[64 + 3 * v + 1] = a1 * 0.125f;
      op[64 + 3 * v + 2] = a2 * 0.125f;
    }
  }
  {
    const int u = lane;
    const float v0 = xrow[64 + 3 * u], v1 = xrow[64 + 3 * u + 1], v2 = xrow[64 + 3 * u + 2];
    f0[u] = xrow[u];
    f0[64 + u] = sqrtf(v0 * v0 + v1 * v1 + v2 * v2);
  }
  __syncthreads();
  {
    float acc0 = gpb1[lane], acc1 = gpb1[64 + lane];
#pragma unroll 4
    for (int k = 0; k < 128; ++k) {
      const float fk = f0[k];
      acc0 += fk * gpW1[k * 128 + lane];
      acc1 += fk * gpW1[k * 128 + 64 + lane];
    }
    t[lane] = siluf(acc0);
    t[64 + lane] = siluf(acc1);
  }
  __syncthreads();
  {
    const int u = lane;
    float g0 = gpb2[u], g1 = gpb2[64 + u];
#pragma unroll 4
    for (int k = 0; k < 128; ++k) {
      const float tk = t[k];
      g0 += tk * gpW2[k * 128 + u];
      g1 += tk * gpW2[k * 128 + 64 + u];
    }
    row2[u] = g0;
    row2[64 + 3 * u + 0] = xrow[64 + 3 * u + 0] * g1;
    row2[64 + 3 * u + 1] = xrow[64 + 3 * u + 1] * g1;
    row2[64 + 3 * u + 2] = xrow[64 + 3 * u + 2] * g1;
  }
  __syncthreads();
  {
    const int v = lane;
    float sa = 0.f, a0 = 0.f, a1 = 0.f, a2 = 0.f;
#pragma unroll 4
    for (int u = 0; u < 64; ++u) {
      const float w0 = Wn0[u * 64 + v];
      const float w1 = Wn1[u * 64 + v];
      sa += row2[u] * w0;
      a0 += row2[64 + 3 * u + 0] * w1;
      a1 += row2[64 + 3 * u + 1] * w1;
      a2 += row2[64 + 3 * u + 2] * w1;
    }
    if (valid) {
      float* op = h + (size_t)node * 256;
      op[v] = sa * 0.125f + bn0[v];
      op[64 + 3 * v + 0] = a0 * 0.125f;
      op[64 + 3 * v + 1] = a1 * 0.125f;
      op[64 + 3 * v + 2] = a2 * 0.125f;
    }
  }
}

// ---- LDS activation arena (shorts, lifetime-aliased) ----
// Phase timeline: P0 build | P1 fs1+fe1 | P2 fe2 | P3 fs2 | P4 TP | P5 g1 | P6 g2 | P7 Wo
//  hidEb  [32][20]  @0      live P0..P2
//  hid2b  [32][68]  @640    live P1..P3
//  s0b    [32][196] @2816   live P0..P1
//  earowb [32][36]  @9088   live P0..P1
//  wb     [32][320] @2816   live P2..P4   (aliases s0b+earowb, +2816 fresh)
//  f0b    [32][132] @13056  live P4..P5
//  pvb    [32][192] @17280  live P4..P6
//  tb     [32][132] @2816   live P5..P6   (aliases dead wb)
//  gated  4x[32][68] @7040  live P6..P7   (aliases dead wb + dead f0b)
#define A_HIDE  0
#define A_HID2  640
#define A_S0    2816
#define A_EA    9088
#define A_WB    2816
#define A_F0    13056
#define A_PV    17280
#define A_TB    2816
#define A_GATED 7040
#define ACT_TOTAL 23424
#define LDS_BYTES (ACT_TOTAL * 2)   // 46848 B => 3 blocks/CU

#define MFMA32(a, b, c) __builtin_amdgcn_mfma_f32_32x32x16_bf16(a, b, c, 0, 0, 0)

__global__ __launch_bounds__(256, 3) void edge_kernel(
    const float* __restrict__ ea,
    const float* __restrict__ npa,
    const float* __restrict__ fsb1, const float* __restrict__ fsb2,
    const float* __restrict__ gb1, const float* __restrict__ gb2,
    const float* __restrict__ bo0,
    const int* __restrict__ eidx,
    const float* __restrict__ na0, const float* __restrict__ h,
    const short* __restrict__ wsb,
    float* __restrict__ out, int E)
{
  extern __shared__ __align__(16) short smem[];
  short* hidEb  = smem + A_HIDE;
  short* hid2b  = smem + A_HID2;
  short* s0b    = smem + A_S0;
  short* earowb = smem + A_EA;
  short* wb     = smem + A_WB;
  short* f0b    = smem + A_F0;
  short* pvb    = smem + A_PV;
  short* tb     = smem + A_TB;
  short* gated  = smem + A_GATED;

  const int tid = threadIdx.x;
  const int wv = tid >> 6, ln = tid & 63;
  const int m32 = ln & 31, kh = ln >> 5;
  const int e0 = blockIdx.x * 32;

  const float C0c = 0.4472135954999579f;   // sqrt(1/5)
  const float C1c = 0.7745966692414834f;   // sqrt(3/5)
  const float iS3 = 0.5773502691896258f;
  const float iS6 = 0.40824829046386307f;
  const float isq32 = 0.17677669529663687f;
  const float isq8 = 0.35355339059327373f;

  // ---- P0: build earow, zero hidE, build s0 ----
  for (int i = tid; i < 32 * 32; i += 256) {
    int e = i >> 5, k = i & 31;
    int eg = e0 + e; if (eg >= E) eg = E - 1;
    earowb[e * 36 + k] = f2b(ea[(size_t)eg * 32 + k]);
  }
  for (int i = tid; i < 640; i += 256) hidEb[i] = 0;
  for (int i = 0; i < 8; ++i) {
    int e = wv * 8 + i;
    int eg = e0 + e; if (eg >= E) eg = E - 1;
    const int dst = eidx[eg], src = eidx[E + eg];
    const float* nd = na0 + (size_t)dst * 256;
    const float* ns = na0 + (size_t)src * 256;
    const int u = ln;
    float ip = nd[64 + 3 * u] * ns[64 + 3 * u] + nd[64 + 3 * u + 1] * ns[64 + 3 * u + 1]
             + nd[64 + 3 * u + 2] * ns[64 + 3 * u + 2];
    s0b[e * 196 + u] = f2b(nd[u]);
    s0b[e * 196 + 64 + u] = f2b(ns[u]);
    s0b[e * 196 + 128 + u] = f2b(ip * (1.f / 3.f));
  }
  __syncthreads();

  // ---- P1: fs1 (waves 0,1): hid2 = silu(s0 @ fsW1 + fsb1); fe1 (wave 2) ----
  if (wv < 2) {
    f32x16 acc = {};
    const int n = wv * 32 + m32;
    const short* A = s0b + m32 * 196 + kh * 8;
    const short* B = wsb + WOFF_FSW1 + n * 200 + kh * 8;
#pragma unroll
    for (int k0 = 0; k0 < 12; ++k0)
      acc = MFMA32(ld8(A + k0 * 16), gld8(B + k0 * 16), acc);
    const float bias = fsb1[n];
#pragma unroll
    for (int r = 0; r < 16; ++r) {
      int row = (r & 3) + 8 * (r >> 2) + 4 * kh;
      hid2b[row * 68 + n] = f2b(siluf(acc[r] + bias));
    }
  } else if (wv == 2) {
    // fe1: hidE = ssp((ea @ feW1) / sqrt(32))
    f32x16 acc = {};
    const short* A = earowb + m32 * 36 + kh * 8;
    const short* B = wsb + WOFF_FEW1 + m32 * 40 + kh * 8;
#pragma unroll
    for (int k0 = 0; k0 < 2; ++k0)
      acc = MFMA32(ld8(A + k0 * 16), gld8(B + k0 * 16), acc);
    if (m32 < 8) {
#pragma unroll
      for (int r = 0; r < 16; ++r) {
        int row = (r & 3) + 8 * (r >> 2) + 4 * kh;
        hidEb[row * 20 + m32] = f2b(sspf(acc[r] * isq32));
      }
    }
  }
  __syncthreads();

  // ---- P2: fe2: fe = (hidE @ feW2) / sqrt(8) -> wb ----
  for (int nt = wv; nt < 10; nt += 4) {
    f32x16 acc = {};
    const int n = nt * 32 + m32;
    acc = MFMA32(ld8(hidEb + m32 * 20 + kh * 8), gld8(wsb + WOFF_FEW2 + n * 24 + kh * 8), acc);
#pragma unroll
    for (int r = 0; r < 16; ++r) {
      int row = (r & 3) + 8 * (r >> 2) + 4 * kh;
      wb[row * 320 + n] = f2b(acc[r] * isq8);
    }
  }
  __syncthreads();

  // ---- P3: fs2: w = (hid2 @ fsW2 + fsb2) * fe  -> wb in place ----
  for (int nt = wv; nt < 10; nt += 4) {
    f32x16 acc = {};
    const int n = nt * 32 + m32;
    const short* A = hid2b + m32 * 68 + kh * 8;
    const short* B = wsb + WOFF_FSW2 + n * 72 + kh * 8;
#pragma unroll
    for (int k0 = 0; k0 < 4; ++k0)
      acc = MFMA32(ld8(A + k0 * 16), gld8(B + k0 * 16), acc);
    const float bias = fsb2[n];
#pragma unroll
    for (int r = 0; r < 16; ++r) {
      int row = (r & 3) + 8 * (r >> 2) + 4 * kh;
      float fsv = acc[r] + bias;
      wb[row * 320 + n] = f2b(fsv * b2f(wb[row * 320 + n]));
    }
  }
  __syncthreads();

  // ---- P4: TP: pair = tp(h[src], h[dst], w) -> f0b (scalars+norms), pvb (vectors) ----
  for (int i = 0; i < 8; ++i) {
    int e = wv * 8 + i;
    int eg = e0 + e; if (eg >= E) eg = E - 1;
    const int dst = eidx[eg], src = eidx[E + eg];
    const float* hs = h + (size_t)src * 256;
    const float* hd = h + (size_t)dst * 256;
    const int u = ln;
    const float w0 = b2f(wb[e * 320 + u]);
    const float w1 = b2f(wb[e * 320 + u + 64]);
    const float w2 = b2f(wb[e * 320 + u + 128]);
    const float w3 = b2f(wb[e * 320 + u + 192]);
    const float w4 = b2f(wb[e * 320 + u + 256]);
    const float xs = hs[u], ys = hd[u];
    const float xv0 = hs[64 + 3 * u], xv1 = hs[64 + 3 * u + 1], xv2 = hs[64 + 3 * u + 2];
    const float yv0 = hd[64 + 3 * u], yv1 = hd[64 + 3 * u + 1], yv2 = hd[64 + 3 * u + 2];
    const float ipv = xv0 * yv0 + xv1 * yv1 + xv2 * yv2;
    const float cr0 = xv1 * yv2 - xv2 * yv1;
    const float cr1 = xv2 * yv0 - xv0 * yv2;
    const float cr2 = xv0 * yv1 - xv1 * yv0;
    const float ps = C0c * (w0 * xs * ys + w3 * ipv * iS3);
    const float k011 = C1c * iS3 * w1 * xs;
    const float k101 = C1c * iS3 * w2 * ys;
    const float k111 = C1c * iS6 * w4;
    const float pv0 = k011 * yv0 + k101 * xv0 + k111 * cr0;
    const float pv1 = k011 * yv1 + k101 * xv1 + k111 * cr1;
    const float pv2 = k011 * yv2 + k101 * xv2 + k111 * cr2;
    f0b[e * 132 + u] = f2b(ps);
    f0b[e * 132 + 64 + u] = f2b(sqrtf(pv0 * pv0 + pv1 * pv1 + pv2 * pv2));
    pvb[e * 192 + 3 * u + 0] = f2b(pv0);
    pvb[e * 192 + 3 * u + 1] = f2b(pv1);
    pvb[e * 192 + 3 * u + 2] = f2b(pv2);
  }
  __syncthreads();

  // ---- P5: g1: t = silu(f0 @ gW1 + gb1) ----
  {
    f32x16 acc = {};
    const int n = wv * 32 + m32;
    const short* A = f0b + m32 * 132 + kh * 8;
    const short* B = wsb + WOFF_GW1 + n * 136 + kh * 8;
#pragma unroll
    for (int k0 = 0; k0 < 8; ++k0)
      acc = MFMA32(ld8(A + k0 * 16), gld8(B + k0 * 16), acc);
    const float bias = gb1[n];
#pragma unroll
    for (int r = 0; r < 16; ++r) {
      int row = (r & 3) + 8 * (r >> 2) + 4 * kh;
      tb[row * 132 + n] = f2b(siluf(acc[r] + bias));
    }
  }
  __syncthreads();

  // ---- P6: g2: g = t @ gW2 + gb2 ; gate -> gated (As scalar, Av_c vector comps) ----
  {
    f32x16 acc = {};
    const int n = wv * 32 + m32;
    const short* A = tb + m32 * 132 + kh * 8;
    const short* B = wsb + WOFF_GW2 + n * 136 + kh * 8;
#pragma unroll
    for (int k0 = 0; k0 < 8; ++k0)
      acc = MFMA32(ld8(A + k0 * 16), gld8(B + k0 * 16), acc);
    const float bias = gb2[n];
#pragma unroll
    for (int r = 0; r < 16; ++r) {
      int row = (r & 3) + 8 * (r >> 2) + 4 * kh;
      float val = acc[r] + bias;
      if (wv < 2) {
        gated[row * 68 + n] = f2b(val);                 // As: gated scalars
      } else {
        int u = n - 64;
        float p0 = b2f(pvb[row * 192 + 3 * u + 0]);
        float p1 = b2f(pvb[row * 192 + 3 * u + 1]);
        float p2 = b2f(pvb[row * 192 + 3 * u + 2]);
        gated[2176 * 1 + row * 68 + u] = f2b(p0 * val);
        gated[2176 * 2 + row * 68 + u] = f2b(p1 * val);
        gated[2176 * 3 + row * 68 + u] = f2b(p2 * val);
      }
    }
  }
  __syncthreads();

  // ---- P7: Wo: out = o3_linear(gated, Wo0, bo0, Wo1) + npa ; wave wv owns comp wv ----
  {
    const short* A = gated + 2176 * wv + m32 * 68 + kh * 8;   // wv=0: As, else Av_{wv-1}
    const short* B0 = wsb + (wv == 0 ? WOFF_WO0 : WOFF_WO1);
    for (int nt = 0; nt < 2; ++nt) {
      f32x16 acc = {};
      const int n = nt * 32 + m32;
      const short* B = B0 + n * 72 + kh * 8;
#pragma unroll
      for (int k0 = 0; k0 < 4; ++k0)
        acc = MFMA32(ld8(A + k0 * 16), gld8(B + k0 * 16), acc);
      const float bias = (wv == 0) ? bo0[n] : 0.f;
      const int off = (wv == 0) ? n : 64 + 3 * n + (wv - 1);
#pragma unroll
      for (int r = 0; r < 16; ++r) {
        int row = (r & 3) + 8 * (r >> 2) + 4 * kh;
        int eg = e0 + row;
        if (eg < E)
          out[(size_t)eg * 256 + off] = acc[r] * 0.125f + bias + npa[(size_t)eg * 256 + off];
      }
    }
  }
}

extern "C" void kernel_launch(void* const* d_in, const int* in_sizes, int n_in,
                              void* d_out, int out_size, void* d_ws, size_t ws_size,
                              hipStream_t stream) {
  const float* node_attr = (const float*)d_in[0];
  const float* edge_attr = (const float*)d_in[1];
  const float* npa  = (const float*)d_in[2];
  const float* Wi0  = (const float*)d_in[3];
  const float* bi0  = (const float*)d_in[4];
  const float* Wi1  = (const float*)d_in[5];
  const float* gpW1 = (const float*)d_in[6];
  const float* gpb1 = (const float*)d_in[7];
  const float* gpW2 = (const float*)d_in[8];
  const float* gpb2 = (const float*)d_in[9];
  const float* Wn0  = (const float*)d_in[10];
  const float* bn0  = (const float*)d_in[11];
  const float* Wn1  = (const float*)d_in[12];
  const float* feW1 = (const float*)d_in[13];
  const float* feW2 = (const float*)d_in[14];
  const float* fsW1 = (const float*)d_in[15];
  const float* fsb1 = (const float*)d_in[16];
  const float* fsW2 = (const float*)d_in[17];
  const float* fsb2 = (const float*)d_in[18];
  const float* gW1  = (const float*)d_in[19];
  const float* gb1  = (const float*)d_in[20];
  const float* gW2  = (const float*)d_in[21];
  const float* gb2  = (const float*)d_in[22];
  const float* Wo0  = (const float*)d_in[23];
  const float* bo0  = (const float*)d_in[24];
  const float* Wo1  = (const float*)d_in[25];
  const int* eidx = (const int*)d_in[26];

  const int N = in_sizes[0] / 256;
  const int E = in_sizes[1] / 32;

  float* na0 = (float*)d_ws;
  float* h = na0 + (size_t)N * 256;
  short* wsb = (short*)(h + (size_t)N * 256);   // bf16 transposed weights (~178 KB)

  (void)hipFuncSetAttribute((const void*)edge_kernel,
                            hipFuncAttributeMaxDynamicSharedMemorySize,
                            LDS_BYTES);

  prep_weights<<<96, 256, 0, stream>>>(fsW1, fsW2, feW1, feW2, gW1, gW2, Wo0, Wo1, wsb);
  node_kernel<<<(N + 3) / 4, 256, 0, stream>>>(node_attr, Wi0, bi0, Wi1, gpW1, gpb1,
                                               gpW2, gpb2, Wn0, bn0, Wn1, na0, h, N);
  edge_kernel<<<(E + 31) / 32, 256, LDS_BYTES, stream>>>(
      edge_attr, npa, fsb1, fsb2, gb1, gb2, bo0, eidx, na0, h, wsb, (float*)d_out, E);
}

// Round 2
// 508.020 us; speedup vs baseline: 1.9658x; 1.1784x over previous
//
#include <hip/hip_runtime.h>
#include <hip/hip_bf16.h>
#include <math.h>

// Round 6: rewrite node_kernel as MFMA-batched GEMMs (32 nodes/block), mirroring the
// edge kernel structure. Precision is preserved via bf16 hi+lo split of activations
// AND weights (3 MFMAs per K-step => ~fp32-accurate GEMM), since na0/h feed the edge
// TP in f32 and absmax sits exactly at threshold. Edge kernel unchanged from round 5.

static __device__ __forceinline__ float siluf(float x) { return x / (1.f + __expf(-x)); }
static __device__ __forceinline__ float sspf(float x) {
  return fmaxf(x, 0.f) + log1pf(__expf(-fabsf(x))) - 0.6931471805599453f;
}
static __device__ __forceinline__ short f2b(float x) {
  __hip_bfloat16 b = __float2bfloat16(x);
  short s; __builtin_memcpy(&s, &b, 2); return s;
}
static __device__ __forceinline__ float b2f(short s) {
  unsigned int u = ((unsigned int)(unsigned short)s) << 16;
  float f; __builtin_memcpy(&f, &u, 4); return f;
}

typedef __attribute__((ext_vector_type(4))) short short4v;
typedef __attribute__((ext_vector_type(8))) short short8v;
typedef __attribute__((ext_vector_type(16))) float f32x16;

// LDS A-fragment load: two ds_read_b64 (strides ≡ 4 mod 8 elems => 8B-aligned)
static __device__ __forceinline__ short8v ld8(const short* p) {
  const short4v* q = (const short4v*)p;
  short4v a = q[0], b = q[1];
  short8v r;
  r[0] = a[0]; r[1] = a[1]; r[2] = a[2]; r[3] = a[3];
  r[4] = b[0]; r[5] = b[1]; r[6] = b[2]; r[7] = b[3];
  return r;
}

// Global B-fragment load: single global_load_dwordx4 (strides multiple of 8 elems)
static __device__ __forceinline__ short8v gld8(const short* __restrict__ p) {
  return *reinterpret_cast<const short8v*>(p);
}

// hi/lo split store (to LDS)
static __device__ __forceinline__ void sp2(short* hp, short* lp, float x) {
  short hh = f2b(x); *hp = hh; *lp = f2b(x - b2f(hh));
}

// ---- bf16 weight table in global ws (elem offsets), all [N][K_pad] transposed ----
// edge weights (single bf16):
#define WOFF_FSW1 0        // fsW1T [64][200]
#define WOFF_FSW2 12800    // fsW2T [320][72]
#define WOFF_FEW1 35840    // feW1T [32][40]
#define WOFF_FEW2 37120    // feW2T [320][24]
#define WOFF_GW1  44800    // gW1T  [128][136]
#define WOFF_GW2  62208    // gW2T  [128][136]
#define WOFF_WO0  79616    // Wo0T  [64][72]
#define WOFF_WO1  84224    // Wo1T  [64][72]
#define W_TOTAL   88832
// node weights (hi tile then lo tile, contiguous):
#define NOFF_WI0  88832    // Wi0T [64][72] x2
#define NOFF_WI1  98048    // Wi1T [64][72] x2
#define NOFF_GP1  107264   // gpW1T [128][136] x2
#define NOFF_GP2  142080   // gpW2T [128][136] x2
#define NOFF_WN0  176896   // Wn0T [64][72] x2
#define NOFF_WN1  186112   // Wn1T [64][72] x2
#define W_ALL     195328

__global__ __launch_bounds__(256) void prep_weights(
    const float* __restrict__ fsW1, const float* __restrict__ fsW2,
    const float* __restrict__ feW1, const float* __restrict__ feW2,
    const float* __restrict__ gW1, const float* __restrict__ gW2,
    const float* __restrict__ Wo0, const float* __restrict__ Wo1,
    const float* __restrict__ Wi0, const float* __restrict__ Wi1,
    const float* __restrict__ gpW1, const float* __restrict__ gpW2,
    const float* __restrict__ Wn0, const float* __restrict__ Wn1,
    short* __restrict__ wsb)
{
  const int gt = blockIdx.x * blockDim.x + threadIdx.x;
  const int gs = gridDim.x * blockDim.x;
  for (int i = gt; i < 64 * 200; i += gs)  { int n = i / 200, k = i % 200; wsb[WOFF_FSW1 + i] = (k < 192) ? f2b(fsW1[k * 64 + n]) : 0; }
  for (int i = gt; i < 320 * 72; i += gs)  { int n = i / 72,  k = i % 72;  wsb[WOFF_FSW2 + i] = (k < 64)  ? f2b(fsW2[k * 320 + n]) : 0; }
  for (int i = gt; i < 32 * 40; i += gs)   { int n = i / 40,  k = i % 40;  wsb[WOFF_FEW1 + i] = (n < 8 && k < 32) ? f2b(feW1[k * 8 + n]) : 0; }
  for (int i = gt; i < 320 * 24; i += gs)  { int n = i / 24,  k = i % 24;  wsb[WOFF_FEW2 + i] = (k < 8)   ? f2b(feW2[k * 320 + n]) : 0; }
  for (int i = gt; i < 128 * 136; i += gs) { int n = i / 136, k = i % 136; wsb[WOFF_GW1 + i]  = (k < 128) ? f2b(gW1[k * 128 + n]) : 0; }
  for (int i = gt; i < 128 * 136; i += gs) { int n = i / 136, k = i % 136; wsb[WOFF_GW2 + i]  = (k < 128) ? f2b(gW2[k * 128 + n]) : 0; }
  for (int i = gt; i < 64 * 72; i += gs)   { int n = i / 72,  k = i % 72;  wsb[WOFF_WO0 + i]  = (k < 64)  ? f2b(Wo0[k * 64 + n]) : 0; }
  for (int i = gt; i < 64 * 72; i += gs)   { int n = i / 72,  k = i % 72;  wsb[WOFF_WO1 + i]  = (k < 64)  ? f2b(Wo1[k * 64 + n]) : 0; }
  // node weights, hi/lo
  for (int i = gt; i < 64 * 72; i += gs)   { int n = i / 72,  k = i % 72;  float w = (k < 64) ? Wi0[k * 64 + n] : 0.f;  short hh = f2b(w); wsb[NOFF_WI0 + i] = hh; wsb[NOFF_WI0 + 4608 + i]  = f2b(w - b2f(hh)); }
  for (int i = gt; i < 64 * 72; i += gs)   { int n = i / 72,  k = i % 72;  float w = (k < 64) ? Wi1[k * 64 + n] : 0.f;  short hh = f2b(w); wsb[NOFF_WI1 + i] = hh; wsb[NOFF_WI1 + 4608 + i]  = f2b(w - b2f(hh)); }
  for (int i = gt; i < 128 * 136; i += gs) { int n = i / 136, k = i % 136; float w = (k < 128) ? gpW1[k * 128 + n] : 0.f; short hh = f2b(w); wsb[NOFF_GP1 + i] = hh; wsb[NOFF_GP1 + 17408 + i] = f2b(w - b2f(hh)); }
  for (int i = gt; i < 128 * 136; i += gs) { int n = i / 136, k = i % 136; float w = (k < 128) ? gpW2[k * 128 + n] : 0.f; short hh = f2b(w); wsb[NOFF_GP2 + i] = hh; wsb[NOFF_GP2 + 17408 + i] = f2b(w - b2f(hh)); }
  for (int i = gt; i < 64 * 72; i += gs)   { int n = i / 72,  k = i % 72;  float w = (k < 64) ? Wn0[k * 64 + n] : 0.f;  short hh = f2b(w); wsb[NOFF_WN0 + i] = hh; wsb[NOFF_WN0 + 4608 + i]  = f2b(w - b2f(hh)); }
  for (int i = gt; i < 64 * 72; i += gs)   { int n = i / 72,  k = i % 72;  float w = (k < 64) ? Wn1[k * 64 + n] : 0.f;  short hh = f2b(w); wsb[NOFF_WN1 + i] = hh; wsb[NOFF_WN1 + 4608 + i]  = f2b(w - b2f(hh)); }
}

#define MFMA32(a, b, c) __builtin_amdgcn_mfma_f32_32x32x16_bf16(a, b, c, 0, 0, 0)

// hi/lo K-step: 3 MFMAs, ~fp32-accurate
#define MFMA_HL(ah, al, bh, bl, acc) \
  do { acc = MFMA32((al), (bh), acc); acc = MFMA32((ah), (bl), acc); acc = MFMA32((ah), (bh), acc); } while (0)

// ---- node kernel LDS arena (shorts, lifetime-aliased) ----
// P0 build | N1 Li0 | N2 g1 | N3 g2+gate | N4 Ln
//  Xs  hi/lo [32][68]  @0/2176       live P0..N1
//  Vc  hi/lo [32][68]  @4352+c*4352  live P0..N1
//  f0  hi/lo [32][132] @17408/21632  live P0..N2
//  tb  hi/lo [32][132] @0/4224       live N2..N3 (aliases Xs+V0)
//  GVc hi/lo [32][68]  @8704+c*4352  live N3..N4 (aliases V1,V2,f0)
//  Gs  hi/lo [32][68]  @21760/23936  live N3..N4 (aliases f0 tail)
#define XS_H 0
#define V0H  4352
#define F0H  17408
#define F0L  21632
#define TBH  0
#define TBL  4224
#define GVH  8704
#define GSH  21760
#define GSL  23936
#define NODE_LDS_SHORTS 26112   // 52224 B => 3 blocks/CU

__global__ __launch_bounds__(256, 3) void node_kernel(
    const float* __restrict__ na,
    const float* __restrict__ bi0, const float* __restrict__ gpb1,
    const float* __restrict__ gpb2, const float* __restrict__ bn0,
    const short* __restrict__ wsb,
    float* __restrict__ na0, float* __restrict__ h, int N)
{
  __shared__ __align__(16) short smem[NODE_LDS_SHORTS];
  const int tid = threadIdx.x;
  const int wv = tid >> 6, ln = tid & 63;
  const int m32 = ln & 31, kh = ln >> 5;
  const int nb0 = blockIdx.x * 32;

  // ---- P0: load 32 x-rows, build hi/lo tiles: Xs, V0..V2, f0=[s,nrm] ----
  for (int i = 0; i < 8; ++i) {
    const int e = wv * 8 + i;
    int ng = nb0 + e; if (ng >= N) ng = N - 1;
    const float* xp = na + (size_t)ng * 256;
    const int u = ln;
    const float xs = xp[u];
    const float v0 = xp[64 + 3 * u], v1 = xp[64 + 3 * u + 1], v2 = xp[64 + 3 * u + 2];
    const float nr = sqrtf(v0 * v0 + v1 * v1 + v2 * v2);
    sp2(smem + XS_H + e * 68 + u,        smem + XS_H + 2176 + e * 68 + u, xs);
    sp2(smem + V0H + 0 * 4352 + e * 68 + u, smem + V0H + 0 * 4352 + 2176 + e * 68 + u, v0);
    sp2(smem + V0H + 1 * 4352 + e * 68 + u, smem + V0H + 1 * 4352 + 2176 + e * 68 + u, v1);
    sp2(smem + V0H + 2 * 4352 + e * 68 + u, smem + V0H + 2 * 4352 + 2176 + e * 68 + u, v2);
    sp2(smem + F0H + e * 132 + u,        smem + F0L + e * 132 + u, xs);
    sp2(smem + F0H + e * 132 + 64 + u,   smem + F0L + e * 132 + 64 + u, nr);
  }
  __syncthreads();

  // ---- N1: Li0 — wave wv owns gemm g=wv (g0: scalars @Wi0; g1..3: comp @Wi1) ----
  {
    const int g = wv;
    const short* Ah = smem + (g == 0 ? XS_H : V0H + (g - 1) * 4352) + m32 * 68 + kh * 8;
    const short* Al = Ah + 2176;
    const int bofs = (g == 0) ? NOFF_WI0 : NOFF_WI1;
    for (int nt = 0; nt < 2; ++nt) {
      f32x16 acc = {};
      const int n = nt * 32 + m32;
      const short* Bh = wsb + bofs + n * 72 + kh * 8;
      const short* Bl = Bh + 4608;
#pragma unroll
      for (int k0 = 0; k0 < 4; ++k0) {
        short8v ah = ld8(Ah + k0 * 16), al = ld8(Al + k0 * 16);
        short8v bh = gld8(Bh + k0 * 16), bl = gld8(Bl + k0 * 16);
        MFMA_HL(ah, al, bh, bl, acc);
      }
      const float bias = (g == 0) ? bi0[n] : 0.f;
      const int off = (g == 0) ? n : 64 + 3 * n + (g - 1);
#pragma unroll
      for (int r = 0; r < 16; ++r) {
        int row = (r & 3) + 8 * (r >> 2) + 4 * kh;
        int ng = nb0 + row;
        if (ng < N) na0[(size_t)ng * 256 + off] = acc[r] * 0.125f + bias;
      }
    }
  }
  __syncthreads();

  // ---- N2: g1 — t = silu(f0 @ gpW1 + gpb1), write tb hi/lo ----
  {
    f32x16 acc = {};
    const int n = wv * 32 + m32;
    const short* Ah = smem + F0H + m32 * 132 + kh * 8;
    const short* Al = smem + F0L + m32 * 132 + kh * 8;
    const short* Bh = wsb + NOFF_GP1 + n * 136 + kh * 8;
    const short* Bl = Bh + 17408;
#pragma unroll
    for (int k0 = 0; k0 < 8; ++k0) {
      short8v ah = ld8(Ah + k0 * 16), al = ld8(Al + k0 * 16);
      short8v bh = gld8(Bh + k0 * 16), bl = gld8(Bl + k0 * 16);
      MFMA_HL(ah, al, bh, bl, acc);
    }
    const float bias = gpb1[n];
#pragma unroll
    for (int r = 0; r < 16; ++r) {
      int row = (r & 3) + 8 * (r >> 2) + 4 * kh;
      float t = siluf(acc[r] + bias);
      sp2(smem + TBH + row * 132 + n, smem + TBL + row * 132 + n, t);
    }
  }
  __syncthreads();

  // ---- N3: g2 — G = tb @ gpW2 + gpb2; gate scalars->Gs, vectors->GVc (v from na, f32) ----
  {
    f32x16 acc = {};
    const int n = wv * 32 + m32;
    const short* Ah = smem + TBH + m32 * 132 + kh * 8;
    const short* Al = smem + TBL + m32 * 132 + kh * 8;
    const short* Bh = wsb + NOFF_GP2 + n * 136 + kh * 8;
    const short* Bl = Bh + 17408;
#pragma unroll
    for (int k0 = 0; k0 < 8; ++k0) {
      short8v ah = ld8(Ah + k0 * 16), al = ld8(Al + k0 * 16);
      short8v bh = gld8(Bh + k0 * 16), bl = gld8(Bl + k0 * 16);
      MFMA_HL(ah, al, bh, bl, acc);
    }
    const float bias = gpb2[n];
#pragma unroll
    for (int r = 0; r < 16; ++r) {
      int row = (r & 3) + 8 * (r >> 2) + 4 * kh;
      float val = acc[r] + bias;
      if (wv < 2) {
        sp2(smem + GSH + row * 68 + n, smem + GSL + row * 68 + n, val);
      } else {
        const int u = n - 64;
        int ng = nb0 + row; if (ng >= N) ng = N - 1;
        const float* vp = na + (size_t)ng * 256 + 64 + 3 * u;
#pragma unroll
        for (int c = 0; c < 3; ++c) {
          float pv = vp[c] * val;
          sp2(smem + GVH + c * 4352 + row * 68 + u,
              smem + GVH + c * 4352 + 2176 + row * 68 + u, pv);
        }
      }
    }
  }
  __syncthreads();

  // ---- N4: Ln — h = o3_linear(gated, Wn0, bn0, Wn1), wave wv owns gemm g=wv ----
  {
    const int g = wv;
    const short* Ah = smem + (g == 0 ? GSH : GVH + (g - 1) * 4352) + m32 * 68 + kh * 8;
    const short* Al = Ah + 2176;
    const int bofs = (g == 0) ? NOFF_WN0 : NOFF_WN1;
    for (int nt = 0; nt < 2; ++nt) {
      f32x16 acc = {};
      const int n = nt * 32 + m32;
      const short* Bh = wsb + bofs + n * 72 + kh * 8;
      const short* Bl = Bh + 4608;
#pragma unroll
      for (int k0 = 0; k0 < 4; ++k0) {
        short8v ah = ld8(Ah + k0 * 16), al = ld8(Al + k0 * 16);
        short8v bh = gld8(Bh + k0 * 16), bl = gld8(Bl + k0 * 16);
        MFMA_HL(ah, al, bh, bl, acc);
      }
      const float bias = (g == 0) ? bn0[n] : 0.f;
      const int off = (g == 0) ? n : 64 + 3 * n + (g - 1);
#pragma unroll
      for (int r = 0; r < 16; ++r) {
        int row = (r & 3) + 8 * (r >> 2) + 4 * kh;
        int ng = nb0 + row;
        if (ng < N) h[(size_t)ng * 256 + off] = acc[r] * 0.125f + bias;
      }
    }
  }
}

// ---- edge kernel LDS arena (unchanged from round 5) ----
#define A_HIDE  0
#define A_HID2  640
#define A_S0    2816
#define A_EA    9088
#define A_WB    2816
#define A_F0    13056
#define A_PV    17280
#define A_TB    2816
#define A_GATED 7040
#define ACT_TOTAL 23424
#define LDS_BYTES (ACT_TOTAL * 2)   // 46848 B => 3 blocks/CU

__global__ __launch_bounds__(256, 3) void edge_kernel(
    const float* __restrict__ ea,
    const float* __restrict__ npa,
    const float* __restrict__ fsb1, const float* __restrict__ fsb2,
    const float* __restrict__ gb1, const float* __restrict__ gb2,
    const float* __restrict__ bo0,
    const int* __restrict__ eidx,
    const float* __restrict__ na0, const float* __restrict__ h,
    const short* __restrict__ wsb,
    float* __restrict__ out, int E)
{
  extern __shared__ __align__(16) short smem[];
  short* hidEb  = smem + A_HIDE;
  short* hid2b  = smem + A_HID2;
  short* s0b    = smem + A_S0;
  short* earowb = smem + A_EA;
  short* wb     = smem + A_WB;
  short* f0b    = smem + A_F0;
  short* pvb    = smem + A_PV;
  short* tb     = smem + A_TB;
  short* gated  = smem + A_GATED;

  const int tid = threadIdx.x;
  const int wv = tid >> 6, ln = tid & 63;
  const int m32 = ln & 31, kh = ln >> 5;
  const int e0 = blockIdx.x * 32;

  const float C0c = 0.4472135954999579f;   // sqrt(1/5)
  const float C1c = 0.7745966692414834f;   // sqrt(3/5)
  const float iS3 = 0.5773502691896258f;
  const float iS6 = 0.40824829046386307f;
  const float isq32 = 0.17677669529663687f;
  const float isq8 = 0.35355339059327373f;

  // ---- P0: build earow, zero hidE, build s0 ----
  for (int i = tid; i < 32 * 32; i += 256) {
    int e = i >> 5, k = i & 31;
    int eg = e0 + e; if (eg >= E) eg = E - 1;
    earowb[e * 36 + k] = f2b(ea[(size_t)eg * 32 + k]);
  }
  for (int i = tid; i < 640; i += 256) hidEb[i] = 0;
  for (int i = 0; i < 8; ++i) {
    int e = wv * 8 + i;
    int eg = e0 + e; if (eg >= E) eg = E - 1;
    const int dst = eidx[eg], src = eidx[E + eg];
    const float* nd = na0 + (size_t)dst * 256;
    const float* ns = na0 + (size_t)src * 256;
    const int u = ln;
    float ip = nd[64 + 3 * u] * ns[64 + 3 * u] + nd[64 + 3 * u + 1] * ns[64 + 3 * u + 1]
             + nd[64 + 3 * u + 2] * ns[64 + 3 * u + 2];
    s0b[e * 196 + u] = f2b(nd[u]);
    s0b[e * 196 + 64 + u] = f2b(ns[u]);
    s0b[e * 196 + 128 + u] = f2b(ip * (1.f / 3.f));
  }
  __syncthreads();

  // ---- P1: fs1 (waves 0,1): hid2 = silu(s0 @ fsW1 + fsb1); fe1 (wave 2) ----
  if (wv < 2) {
    f32x16 acc = {};
    const int n = wv * 32 + m32;
    const short* A = s0b + m32 * 196 + kh * 8;
    const short* B = wsb + WOFF_FSW1 + n * 200 + kh * 8;
#pragma unroll
    for (int k0 = 0; k0 < 12; ++k0)
      acc = MFMA32(ld8(A + k0 * 16), gld8(B + k0 * 16), acc);
    const float bias = fsb1[n];
#pragma unroll
    for (int r = 0; r < 16; ++r) {
      int row = (r & 3) + 8 * (r >> 2) + 4 * kh;
      hid2b[row * 68 + n] = f2b(siluf(acc[r] + bias));
    }
  } else if (wv == 2) {
    f32x16 acc = {};
    const short* A = earowb + m32 * 36 + kh * 8;
    const short* B = wsb + WOFF_FEW1 + m32 * 40 + kh * 8;
#pragma unroll
    for (int k0 = 0; k0 < 2; ++k0)
      acc = MFMA32(ld8(A + k0 * 16), gld8(B + k0 * 16), acc);
    if (m32 < 8) {
#pragma unroll
      for (int r = 0; r < 16; ++r) {
        int row = (r & 3) + 8 * (r >> 2) + 4 * kh;
        hidEb[row * 20 + m32] = f2b(sspf(acc[r] * isq32));
      }
    }
  }
  __syncthreads();

  // ---- P2: fe2: fe = (hidE @ feW2) / sqrt(8) -> wb ----
  for (int nt = wv; nt < 10; nt += 4) {
    f32x16 acc = {};
    const int n = nt * 32 + m32;
    acc = MFMA32(ld8(hidEb + m32 * 20 + kh * 8), gld8(wsb + WOFF_FEW2 + n * 24 + kh * 8), acc);
#pragma unroll
    for (int r = 0; r < 16; ++r) {
      int row = (r & 3) + 8 * (r >> 2) + 4 * kh;
      wb[row * 320 + n] = f2b(acc[r] * isq8);
    }
  }
  __syncthreads();

  // ---- P3: fs2: w = (hid2 @ fsW2 + fsb2) * fe -> wb in place ----
  for (int nt = wv; nt < 10; nt += 4) {
    f32x16 acc = {};
    const int n = nt * 32 + m32;
    const short* A = hid2b + m32 * 68 + kh * 8;
    const short* B = wsb + WOFF_FSW2 + n * 72 + kh * 8;
#pragma unroll
    for (int k0 = 0; k0 < 4; ++k0)
      acc = MFMA32(ld8(A + k0 * 16), gld8(B + k0 * 16), acc);
    const float bias = fsb2[n];
#pragma unroll
    for (int r = 0; r < 16; ++r) {
      int row = (r & 3) + 8 * (r >> 2) + 4 * kh;
      float fsv = acc[r] + bias;
      wb[row * 320 + n] = f2b(fsv * b2f(wb[row * 320 + n]));
    }
  }
  __syncthreads();

  // ---- P4: TP -> f0b (scalars+norms), pvb (vectors) ----
  for (int i = 0; i < 8; ++i) {
    int e = wv * 8 + i;
    int eg = e0 + e; if (eg >= E) eg = E - 1;
    const int dst = eidx[eg], src = eidx[E + eg];
    const float* hs = h + (size_t)src * 256;
    const float* hd = h + (size_t)dst * 256;
    const int u = ln;
    const float w0 = b2f(wb[e * 320 + u]);
    const float w1 = b2f(wb[e * 320 + u + 64]);
    const float w2 = b2f(wb[e * 320 + u + 128]);
    const float w3 = b2f(wb[e * 320 + u + 192]);
    const float w4 = b2f(wb[e * 320 + u + 256]);
    const float xs = hs[u], ys = hd[u];
    const float xv0 = hs[64 + 3 * u], xv1 = hs[64 + 3 * u + 1], xv2 = hs[64 + 3 * u + 2];
    const float yv0 = hd[64 + 3 * u], yv1 = hd[64 + 3 * u + 1], yv2 = hd[64 + 3 * u + 2];
    const float ipv = xv0 * yv0 + xv1 * yv1 + xv2 * yv2;
    const float cr0 = xv1 * yv2 - xv2 * yv1;
    const float cr1 = xv2 * yv0 - xv0 * yv2;
    const float cr2 = xv0 * yv1 - xv1 * yv0;
    const float ps = C0c * (w0 * xs * ys + w3 * ipv * iS3);
    const float k011 = C1c * iS3 * w1 * xs;
    const float k101 = C1c * iS3 * w2 * ys;
    const float k111 = C1c * iS6 * w4;
    const float pv0 = k011 * yv0 + k101 * xv0 + k111 * cr0;
    const float pv1 = k011 * yv1 + k101 * xv1 + k111 * cr1;
    const float pv2 = k011 * yv2 + k101 * xv2 + k111 * cr2;
    f0b[e * 132 + u] = f2b(ps);
    f0b[e * 132 + 64 + u] = f2b(sqrtf(pv0 * pv0 + pv1 * pv1 + pv2 * pv2));
    pvb[e * 192 + 3 * u + 0] = f2b(pv0);
    pvb[e * 192 + 3 * u + 1] = f2b(pv1);
    pvb[e * 192 + 3 * u + 2] = f2b(pv2);
  }
  __syncthreads();

  // ---- P5: g1: t = silu(f0 @ gW1 + gb1) ----
  {
    f32x16 acc = {};
    const int n = wv * 32 + m32;
    const short* A = f0b + m32 * 132 + kh * 8;
    const short* B = wsb + WOFF_GW1 + n * 136 + kh * 8;
#pragma unroll
    for (int k0 = 0; k0 < 8; ++k0)
      acc = MFMA32(ld8(A + k0 * 16), gld8(B + k0 * 16), acc);
    const float bias = gb1[n];
#pragma unroll
    for (int r = 0; r < 16; ++r) {
      int row = (r & 3) + 8 * (r >> 2) + 4 * kh;
      tb[row * 132 + n] = f2b(siluf(acc[r] + bias));
    }
  }
  __syncthreads();

  // ---- P6: g2: g = t @ gW2 + gb2 ; gate -> gated ----
  {
    f32x16 acc = {};
    const int n = wv * 32 + m32;
    const short* A = tb + m32 * 132 + kh * 8;
    const short* B = wsb + WOFF_GW2 + n * 136 + kh * 8;
#pragma unroll
    for (int k0 = 0; k0 < 8; ++k0)
      acc = MFMA32(ld8(A + k0 * 16), gld8(B + k0 * 16), acc);
    const float bias = gb2[n];
#pragma unroll
    for (int r = 0; r < 16; ++r) {
      int row = (r & 3) + 8 * (r >> 2) + 4 * kh;
      float val = acc[r] + bias;
      if (wv < 2) {
        gated[row * 68 + n] = f2b(val);
      } else {
        int u = n - 64;
        float p0 = b2f(pvb[row * 192 + 3 * u + 0]);
        float p1 = b2f(pvb[row * 192 + 3 * u + 1]);
        float p2 = b2f(pvb[row * 192 + 3 * u + 2]);
        gated[2176 * 1 + row * 68 + u] = f2b(p0 * val);
        gated[2176 * 2 + row * 68 + u] = f2b(p1 * val);
        gated[2176 * 3 + row * 68 + u] = f2b(p2 * val);
      }
    }
  }
  __syncthreads();

  // ---- P7: Wo: out = o3_linear(gated) + npa ----
  {
    const short* A = gated + 2176 * wv + m32 * 68 + kh * 8;
    const short* B0 = wsb + (wv == 0 ? WOFF_WO0 : WOFF_WO1);
    for (int nt = 0; nt < 2; ++nt) {
      f32x16 acc = {};
      const int n = nt * 32 + m32;
      const short* B = B0 + n * 72 + kh * 8;
#pragma unroll
      for (int k0 = 0; k0 < 4; ++k0)
        acc = MFMA32(ld8(A + k0 * 16), gld8(B + k0 * 16), acc);
      const float bias = (wv == 0) ? bo0[n] : 0.f;
      const int off = (wv == 0) ? n : 64 + 3 * n + (wv - 1);
#pragma unroll
      for (int r = 0; r < 16; ++r) {
        int row = (r & 3) + 8 * (r >> 2) + 4 * kh;
        int eg = e0 + row;
        if (eg < E)
          out[(size_t)eg * 256 + off] = acc[r] * 0.125f + bias + npa[(size_t)eg * 256 + off];
      }
    }
  }
}

extern "C" void kernel_launch(void* const* d_in, const int* in_sizes, int n_in,
                              void* d_out, int out_size, void* d_ws, size_t ws_size,
                              hipStream_t stream) {
  const float* node_attr = (const float*)d_in[0];
  const float* edge_attr = (const float*)d_in[1];
  const float* npa  = (const float*)d_in[2];
  const float* Wi0  = (const float*)d_in[3];
  const float* bi0  = (const float*)d_in[4];
  const float* Wi1  = (const float*)d_in[5];
  const float* gpW1 = (const float*)d_in[6];
  const float* gpb1 = (const float*)d_in[7];
  const float* gpW2 = (const float*)d_in[8];
  const float* gpb2 = (const float*)d_in[9];
  const float* Wn0  = (const float*)d_in[10];
  const float* bn0  = (const float*)d_in[11];
  const float* Wn1  = (const float*)d_in[12];
  const float* feW1 = (const float*)d_in[13];
  const float* feW2 = (const float*)d_in[14];
  const float* fsW1 = (const float*)d_in[15];
  const float* fsb1 = (const float*)d_in[16];
  const float* fsW2 = (const float*)d_in[17];
  const float* fsb2 = (const float*)d_in[18];
  const float* gW1  = (const float*)d_in[19];
  const float* gb1  = (const float*)d_in[20];
  const float* gW2  = (const float*)d_in[21];
  const float* gb2  = (const float*)d_in[22];
  const float* Wo0  = (const float*)d_in[23];
  const float* bo0  = (const float*)d_in[24];
  const float* Wo1  = (const float*)d_in[25];
  const int* eidx = (const int*)d_in[26];

  const int N = in_sizes[0] / 256;
  const int E = in_sizes[1] / 32;

  float* na0 = (float*)d_ws;
  float* h = na0 + (size_t)N * 256;
  short* wsb = (short*)(h + (size_t)N * 256);   // bf16 weight table (~390 KB)

  (void)hipFuncSetAttribute((const void*)edge_kernel,
                            hipFuncAttributeMaxDynamicSharedMemorySize,
                            LDS_BYTES);

  prep_weights<<<96, 256, 0, stream>>>(fsW1, fsW2, feW1, feW2, gW1, gW2, Wo0, Wo1,
                                       Wi0, Wi1, gpW1, gpW2, Wn0, Wn1, wsb);
  node_kernel<<<(N + 31) / 32, 256, 0, stream>>>(node_attr, bi0, gpb1, gpb2, bn0,
                                                 wsb, na0, h, N);
  edge_kernel<<<(E + 31) / 32, 256, LDS_BYTES, stream>>>(
      edge_attr, npa, fsb1, fsb2, gb1, gb2, bo0, eidx, na0, h, wsb, (float*)d_out, E);
}

// Round 3
// 502.832 us; speedup vs baseline: 1.9861x; 1.0103x over previous
//
#include <hip/hip_runtime.h>
#include <hip/hip_bf16.h>
#include <math.h>

// Round 7: fragment-major weight packing. All weight tables repacked as
// [k0][n][kh][j=8] so every MFMA B-fragment load is a fully coalesced 1KB
// contiguous wave read (was: 64-lane gather at 144B stride = ~64 cache lines
// per instruction). Node k-loops get #pragma unroll 2 + (256,2) reg cap as a
// spill hedge. Edge kernel structure otherwise unchanged from round 5.

static __device__ __forceinline__ float siluf(float x) { return x / (1.f + __expf(-x)); }
static __device__ __forceinline__ float sspf(float x) {
  return fmaxf(x, 0.f) + log1pf(__expf(-fabsf(x))) - 0.6931471805599453f;
}
static __device__ __forceinline__ short f2b(float x) {
  __hip_bfloat16 b = __float2bfloat16(x);
  short s; __builtin_memcpy(&s, &b, 2); return s;
}
static __device__ __forceinline__ float b2f(short s) {
  unsigned int u = ((unsigned int)(unsigned short)s) << 16;
  float f; __builtin_memcpy(&f, &u, 4); return f;
}

typedef __attribute__((ext_vector_type(4))) short short4v;
typedef __attribute__((ext_vector_type(8))) short short8v;
typedef __attribute__((ext_vector_type(16))) float f32x16;

// LDS A-fragment load: two ds_read_b64 (strides ≡ 4 mod 8 elems => 8B-aligned)
static __device__ __forceinline__ short8v ld8(const short* p) {
  const short4v* q = (const short4v*)p;
  short4v a = q[0], b = q[1];
  short8v r;
  r[0] = a[0]; r[1] = a[1]; r[2] = a[2]; r[3] = a[3];
  r[4] = b[0]; r[5] = b[1]; r[6] = b[2]; r[7] = b[3];
  return r;
}

// Global B-fragment load: single global_load_dwordx4; with fragment-major layout
// the 64 lanes of a wave read one contiguous 1KB chunk.
static __device__ __forceinline__ short8v gld8(const short* __restrict__ p) {
  return *reinterpret_cast<const short8v*>(p);
}

// hi/lo split store (to LDS)
static __device__ __forceinline__ void sp2(short* hp, short* lp, float x) {
  short hh = f2b(x); *hp = hh; *lp = f2b(x - b2f(hh));
}

// ---- fragment-major bf16 weight table (elem offsets) ----
// layout: elem = ((k0*Ntot + n)*2 + kh)*8 + j ; value = W[k0*16 + kh*8 + j][n]
// edge (single bf16):
#define WOFF_FSW1 0        // Ntot=64,  K=192: 12288
#define WOFF_FSW2 12288    // Ntot=320, K=64:  20480
#define WOFF_FEW1 32768    // Ntot=32,  K=32:  1024
#define WOFF_FEW2 33792    // Ntot=320, K=16:  5120
#define WOFF_GW1  38912    // Ntot=128, K=128: 16384
#define WOFF_GW2  55296    // 16384
#define WOFF_WO0  71680    // Ntot=64,  K=64:  4096
#define WOFF_WO1  75776    // 4096
// node (hi table then lo table, each fragment-major):
#define NOFF_WI0  79872    // 4096 x2
#define NOFF_WI1  88064    // 4096 x2
#define NOFF_GP1  96256    // 16384 x2
#define NOFF_GP2  129024   // 16384 x2
#define NOFF_WN0  161792   // 4096 x2
#define NOFF_WN1  169984   // 4096 x2
#define W_ALL     178176

__global__ __launch_bounds__(256) void prep_weights(
    const float* __restrict__ fsW1, const float* __restrict__ fsW2,
    const float* __restrict__ feW1, const float* __restrict__ feW2,
    const float* __restrict__ gW1, const float* __restrict__ gW2,
    const float* __restrict__ Wo0, const float* __restrict__ Wo1,
    const float* __restrict__ Wi0, const float* __restrict__ Wi1,
    const float* __restrict__ gpW1, const float* __restrict__ gpW2,
    const float* __restrict__ Wn0, const float* __restrict__ Wn1,
    short* __restrict__ wsb)
{
  const int gt = blockIdx.x * blockDim.x + threadIdx.x;
  const int gs = gridDim.x * blockDim.x;
  // decode: k0 = i/(Ntot*16); n = (i%(Ntot*16))/16; f = i&15; k = k0*16+f
  // edge weights (single bf16)
  for (int i = gt; i < 12288; i += gs) { int k = (i >> 10) * 16 + (i & 15), n = (i >> 4) & 63;  wsb[WOFF_FSW1 + i] = f2b(fsW1[k * 64 + n]); }
  for (int i = gt; i < 20480; i += gs) { int k = (i / 5120) * 16 + (i & 15), n = (i >> 4) % 320; wsb[WOFF_FSW2 + i] = f2b(fsW2[k * 320 + n]); }
  for (int i = gt; i < 1024; i += gs)  { int k = (i >> 9) * 16 + (i & 15),  n = (i >> 4) & 31;  wsb[WOFF_FEW1 + i] = (n < 8) ? f2b(feW1[k * 8 + n]) : 0; }
  for (int i = gt; i < 5120; i += gs)  { int k = i & 15,                    n = (i >> 4) % 320; wsb[WOFF_FEW2 + i] = (k < 8) ? f2b(feW2[k * 320 + n]) : 0; }
  for (int i = gt; i < 16384; i += gs) { int k = (i >> 11) * 16 + (i & 15), n = (i >> 4) & 127; wsb[WOFF_GW1 + i] = f2b(gW1[k * 128 + n]); }
  for (int i = gt; i < 16384; i += gs) { int k = (i >> 11) * 16 + (i & 15), n = (i >> 4) & 127; wsb[WOFF_GW2 + i] = f2b(gW2[k * 128 + n]); }
  for (int i = gt; i < 4096; i += gs)  { int k = (i >> 10) * 16 + (i & 15), n = (i >> 4) & 63;  wsb[WOFF_WO0 + i] = f2b(Wo0[k * 64 + n]); }
  for (int i = gt; i < 4096; i += gs)  { int k = (i >> 10) * 16 + (i & 15), n = (i >> 4) & 63;  wsb[WOFF_WO1 + i] = f2b(Wo1[k * 64 + n]); }
  // node weights, hi/lo
  for (int i = gt; i < 4096; i += gs)  { int k = (i >> 10) * 16 + (i & 15), n = (i >> 4) & 63;  float w = Wi0[k * 64 + n];  short hh = f2b(w); wsb[NOFF_WI0 + i] = hh; wsb[NOFF_WI0 + 4096 + i] = f2b(w - b2f(hh)); }
  for (int i = gt; i < 4096; i += gs)  { int k = (i >> 10) * 16 + (i & 15), n = (i >> 4) & 63;  float w = Wi1[k * 64 + n];  short hh = f2b(w); wsb[NOFF_WI1 + i] = hh; wsb[NOFF_WI1 + 4096 + i] = f2b(w - b2f(hh)); }
  for (int i = gt; i < 16384; i += gs) { int k = (i >> 11) * 16 + (i & 15), n = (i >> 4) & 127; float w = gpW1[k * 128 + n]; short hh = f2b(w); wsb[NOFF_GP1 + i] = hh; wsb[NOFF_GP1 + 16384 + i] = f2b(w - b2f(hh)); }
  for (int i = gt; i < 16384; i += gs) { int k = (i >> 11) * 16 + (i & 15), n = (i >> 4) & 127; float w = gpW2[k * 128 + n]; short hh = f2b(w); wsb[NOFF_GP2 + i] = hh; wsb[NOFF_GP2 + 16384 + i] = f2b(w - b2f(hh)); }
  for (int i = gt; i < 4096; i += gs)  { int k = (i >> 10) * 16 + (i & 15), n = (i >> 4) & 63;  float w = Wn0[k * 64 + n];  short hh = f2b(w); wsb[NOFF_WN0 + i] = hh; wsb[NOFF_WN0 + 4096 + i] = f2b(w - b2f(hh)); }
  for (int i = gt; i < 4096; i += gs)  { int k = (i >> 10) * 16 + (i & 15), n = (i >> 4) & 63;  float w = Wn1[k * 64 + n];  short hh = f2b(w); wsb[NOFF_WN1 + i] = hh; wsb[NOFF_WN1 + 4096 + i] = f2b(w - b2f(hh)); }
}

#define MFMA32(a, b, c) __builtin_amdgcn_mfma_f32_32x32x16_bf16(a, b, c, 0, 0, 0)

// hi/lo K-step: 3 MFMAs, ~fp32-accurate
#define MFMA_HL(ah, al, bh, bl, acc) \
  do { acc = MFMA32((al), (bh), acc); acc = MFMA32((ah), (bl), acc); acc = MFMA32((ah), (bh), acc); } while (0)

// ---- node kernel LDS arena (shorts, lifetime-aliased) ----
#define XS_H 0
#define V0H  4352
#define F0H  17408
#define F0L  21632
#define TBH  0
#define TBL  4224
#define GVH  8704
#define GSH  21760
#define GSL  23936
#define NODE_LDS_SHORTS 26112   // 52224 B => 3 blocks/CU (LDS-limited)

__global__ __launch_bounds__(256, 2) void node_kernel(
    const float* __restrict__ na,
    const float* __restrict__ bi0, const float* __restrict__ gpb1,
    const float* __restrict__ gpb2, const float* __restrict__ bn0,
    const short* __restrict__ wsb,
    float* __restrict__ na0, float* __restrict__ h, int N)
{
  __shared__ __align__(16) short smem[NODE_LDS_SHORTS];
  const int tid = threadIdx.x;
  const int wv = tid >> 6, ln = tid & 63;
  const int m32 = ln & 31, kh = ln >> 5;
  const int nb0 = blockIdx.x * 32;

  // ---- P0: load 32 x-rows, build hi/lo tiles: Xs, V0..V2, f0=[s,nrm] ----
  for (int i = 0; i < 8; ++i) {
    const int e = wv * 8 + i;
    int ng = nb0 + e; if (ng >= N) ng = N - 1;
    const float* xp = na + (size_t)ng * 256;
    const int u = ln;
    const float xs = xp[u];
    const float v0 = xp[64 + 3 * u], v1 = xp[64 + 3 * u + 1], v2 = xp[64 + 3 * u + 2];
    const float nr = sqrtf(v0 * v0 + v1 * v1 + v2 * v2);
    sp2(smem + XS_H + e * 68 + u,        smem + XS_H + 2176 + e * 68 + u, xs);
    sp2(smem + V0H + 0 * 4352 + e * 68 + u, smem + V0H + 0 * 4352 + 2176 + e * 68 + u, v0);
    sp2(smem + V0H + 1 * 4352 + e * 68 + u, smem + V0H + 1 * 4352 + 2176 + e * 68 + u, v1);
    sp2(smem + V0H + 2 * 4352 + e * 68 + u, smem + V0H + 2 * 4352 + 2176 + e * 68 + u, v2);
    sp2(smem + F0H + e * 132 + u,        smem + F0L + e * 132 + u, xs);
    sp2(smem + F0H + e * 132 + 64 + u,   smem + F0L + e * 132 + 64 + u, nr);
  }
  __syncthreads();

  // ---- N1: Li0 — wave wv owns gemm g=wv (g0: scalars @Wi0; g1..3: comp @Wi1) ----
  {
    const int g = wv;
    const short* Ah = smem + (g == 0 ? XS_H : V0H + (g - 1) * 4352) + m32 * 68 + kh * 8;
    const short* Al = Ah + 2176;
    const int bofs = (g == 0) ? NOFF_WI0 : NOFF_WI1;
    for (int nt = 0; nt < 2; ++nt) {
      f32x16 acc = {};
      const int n = nt * 32 + m32;
      const short* Bh = wsb + bofs + n * 16 + kh * 8;
      const short* Bl = Bh + 4096;
#pragma unroll 2
      for (int k0 = 0; k0 < 4; ++k0) {
        short8v ah = ld8(Ah + k0 * 16), al = ld8(Al + k0 * 16);
        short8v bh = gld8(Bh + k0 * 1024), bl = gld8(Bl + k0 * 1024);
        MFMA_HL(ah, al, bh, bl, acc);
      }
      const float bias = (g == 0) ? bi0[n] : 0.f;
      const int off = (g == 0) ? n : 64 + 3 * n + (g - 1);
#pragma unroll
      for (int r = 0; r < 16; ++r) {
        int row = (r & 3) + 8 * (r >> 2) + 4 * kh;
        int ng = nb0 + row;
        if (ng < N) na0[(size_t)ng * 256 + off] = acc[r] * 0.125f + bias;
      }
    }
  }
  __syncthreads();

  // ---- N2: g1 — t = silu(f0 @ gpW1 + gpb1), write tb hi/lo ----
  {
    f32x16 acc = {};
    const int n = wv * 32 + m32;
    const short* Ah = smem + F0H + m32 * 132 + kh * 8;
    const short* Al = smem + F0L + m32 * 132 + kh * 8;
    const short* Bh = wsb + NOFF_GP1 + n * 16 + kh * 8;
    const short* Bl = Bh + 16384;
#pragma unroll 2
    for (int k0 = 0; k0 < 8; ++k0) {
      short8v ah = ld8(Ah + k0 * 16), al = ld8(Al + k0 * 16);
      short8v bh = gld8(Bh + k0 * 2048), bl = gld8(Bl + k0 * 2048);
      MFMA_HL(ah, al, bh, bl, acc);
    }
    const float bias = gpb1[n];
#pragma unroll
    for (int r = 0; r < 16; ++r) {
      int row = (r & 3) + 8 * (r >> 2) + 4 * kh;
      float t = siluf(acc[r] + bias);
      sp2(smem + TBH + row * 132 + n, smem + TBL + row * 132 + n, t);
    }
  }
  __syncthreads();

  // ---- N3: g2 — G = tb @ gpW2 + gpb2; gate scalars->Gs, vectors->GVc ----
  {
    f32x16 acc = {};
    const int n = wv * 32 + m32;
    const short* Ah = smem + TBH + m32 * 132 + kh * 8;
    const short* Al = smem + TBL + m32 * 132 + kh * 8;
    const short* Bh = wsb + NOFF_GP2 + n * 16 + kh * 8;
    const short* Bl = Bh + 16384;
#pragma unroll 2
    for (int k0 = 0; k0 < 8; ++k0) {
      short8v ah = ld8(Ah + k0 * 16), al = ld8(Al + k0 * 16);
      short8v bh = gld8(Bh + k0 * 2048), bl = gld8(Bl + k0 * 2048);
      MFMA_HL(ah, al, bh, bl, acc);
    }
    const float bias = gpb2[n];
#pragma unroll
    for (int r = 0; r < 16; ++r) {
      int row = (r & 3) + 8 * (r >> 2) + 4 * kh;
      float val = acc[r] + bias;
      if (wv < 2) {
        sp2(smem + GSH + row * 68 + n, smem + GSL + row * 68 + n, val);
      } else {
        const int u = n - 64;
        int ng = nb0 + row; if (ng >= N) ng = N - 1;
        const float* vp = na + (size_t)ng * 256 + 64 + 3 * u;
#pragma unroll
        for (int c = 0; c < 3; ++c) {
          float pv = vp[c] * val;
          sp2(smem + GVH + c * 4352 + row * 68 + u,
              smem + GVH + c * 4352 + 2176 + row * 68 + u, pv);
        }
      }
    }
  }
  __syncthreads();

  // ---- N4: Ln — h = o3_linear(gated, Wn0, bn0, Wn1), wave wv owns gemm g=wv ----
  {
    const int g = wv;
    const short* Ah = smem + (g == 0 ? GSH : GVH + (g - 1) * 4352) + m32 * 68 + kh * 8;
    const short* Al = Ah + 2176;
    const int bofs = (g == 0) ? NOFF_WN0 : NOFF_WN1;
    for (int nt = 0; nt < 2; ++nt) {
      f32x16 acc = {};
      const int n = nt * 32 + m32;
      const short* Bh = wsb + bofs + n * 16 + kh * 8;
      const short* Bl = Bh + 4096;
#pragma unroll 2
      for (int k0 = 0; k0 < 4; ++k0) {
        short8v ah = ld8(Ah + k0 * 16), al = ld8(Al + k0 * 16);
        short8v bh = gld8(Bh + k0 * 1024), bl = gld8(Bl + k0 * 1024);
        MFMA_HL(ah, al, bh, bl, acc);
      }
      const float bias = (g == 0) ? bn0[n] : 0.f;
      const int off = (g == 0) ? n : 64 + 3 * n + (g - 1);
#pragma unroll
      for (int r = 0; r < 16; ++r) {
        int row = (r & 3) + 8 * (r >> 2) + 4 * kh;
        int ng = nb0 + row;
        if (ng < N) h[(size_t)ng * 256 + off] = acc[r] * 0.125f + bias;
      }
    }
  }
}

// ---- edge kernel LDS arena (unchanged) ----
#define A_HIDE  0
#define A_HID2  640
#define A_S0    2816
#define A_EA    9088
#define A_WB    2816
#define A_F0    13056
#define A_PV    17280
#define A_TB    2816
#define A_GATED 7040
#define ACT_TOTAL 23424
#define LDS_BYTES (ACT_TOTAL * 2)   // 46848 B => 3 blocks/CU

__global__ __launch_bounds__(256, 3) void edge_kernel(
    const float* __restrict__ ea,
    const float* __restrict__ npa,
    const float* __restrict__ fsb1, const float* __restrict__ fsb2,
    const float* __restrict__ gb1, const float* __restrict__ gb2,
    const float* __restrict__ bo0,
    const int* __restrict__ eidx,
    const float* __restrict__ na0, const float* __restrict__ h,
    const short* __restrict__ wsb,
    float* __restrict__ out, int E)
{
  extern __shared__ __align__(16) short smem[];
  short* hidEb  = smem + A_HIDE;
  short* hid2b  = smem + A_HID2;
  short* s0b    = smem + A_S0;
  short* earowb = smem + A_EA;
  short* wb     = smem + A_WB;
  short* f0b    = smem + A_F0;
  short* pvb    = smem + A_PV;
  short* tb     = smem + A_TB;
  short* gated  = smem + A_GATED;

  const int tid = threadIdx.x;
  const int wv = tid >> 6, ln = tid & 63;
  const int m32 = ln & 31, kh = ln >> 5;
  const int e0 = blockIdx.x * 32;

  const float C0c = 0.4472135954999579f;   // sqrt(1/5)
  const float C1c = 0.7745966692414834f;   // sqrt(3/5)
  const float iS3 = 0.5773502691896258f;
  const float iS6 = 0.40824829046386307f;
  const float isq32 = 0.17677669529663687f;
  const float isq8 = 0.35355339059327373f;

  // ---- P0: build earow, zero hidE, build s0 ----
  for (int i = tid; i < 32 * 32; i += 256) {
    int e = i >> 5, k = i & 31;
    int eg = e0 + e; if (eg >= E) eg = E - 1;
    earowb[e * 36 + k] = f2b(ea[(size_t)eg * 32 + k]);
  }
  for (int i = tid; i < 640; i += 256) hidEb[i] = 0;
  for (int i = 0; i < 8; ++i) {
    int e = wv * 8 + i;
    int eg = e0 + e; if (eg >= E) eg = E - 1;
    const int dst = eidx[eg], src = eidx[E + eg];
    const float* nd = na0 + (size_t)dst * 256;
    const float* ns = na0 + (size_t)src * 256;
    const int u = ln;
    float ip = nd[64 + 3 * u] * ns[64 + 3 * u] + nd[64 + 3 * u + 1] * ns[64 + 3 * u + 1]
             + nd[64 + 3 * u + 2] * ns[64 + 3 * u + 2];
    s0b[e * 196 + u] = f2b(nd[u]);
    s0b[e * 196 + 64 + u] = f2b(ns[u]);
    s0b[e * 196 + 128 + u] = f2b(ip * (1.f / 3.f));
  }
  __syncthreads();

  // ---- P1: fs1 (waves 0,1): hid2 = silu(s0 @ fsW1 + fsb1); fe1 (wave 2) ----
  if (wv < 2) {
    f32x16 acc = {};
    const int n = wv * 32 + m32;
    const short* A = s0b + m32 * 196 + kh * 8;
    const short* B = wsb + WOFF_FSW1 + n * 16 + kh * 8;
#pragma unroll
    for (int k0 = 0; k0 < 12; ++k0)
      acc = MFMA32(ld8(A + k0 * 16), gld8(B + k0 * 1024), acc);
    const float bias = fsb1[n];
#pragma unroll
    for (int r = 0; r < 16; ++r) {
      int row = (r & 3) + 8 * (r >> 2) + 4 * kh;
      hid2b[row * 68 + n] = f2b(siluf(acc[r] + bias));
    }
  } else if (wv == 2) {
    f32x16 acc = {};
    const short* A = earowb + m32 * 36 + kh * 8;
    const short* B = wsb + WOFF_FEW1 + m32 * 16 + kh * 8;
#pragma unroll
    for (int k0 = 0; k0 < 2; ++k0)
      acc = MFMA32(ld8(A + k0 * 16), gld8(B + k0 * 512), acc);
    if (m32 < 8) {
#pragma unroll
      for (int r = 0; r < 16; ++r) {
        int row = (r & 3) + 8 * (r >> 2) + 4 * kh;
        hidEb[row * 20 + m32] = f2b(sspf(acc[r] * isq32));
      }
    }
  }
  __syncthreads();

  // ---- P2: fe2: fe = (hidE @ feW2) / sqrt(8) -> wb ----
  for (int nt = wv; nt < 10; nt += 4) {
    f32x16 acc = {};
    const int n = nt * 32 + m32;
    acc = MFMA32(ld8(hidEb + m32 * 20 + kh * 8), gld8(wsb + WOFF_FEW2 + n * 16 + kh * 8), acc);
#pragma unroll
    for (int r = 0; r < 16; ++r) {
      int row = (r & 3) + 8 * (r >> 2) + 4 * kh;
      wb[row * 320 + n] = f2b(acc[r] * isq8);
    }
  }
  __syncthreads();

  // ---- P3: fs2: w = (hid2 @ fsW2 + fsb2) * fe -> wb in place ----
  for (int nt = wv; nt < 10; nt += 4) {
    f32x16 acc = {};
    const int n = nt * 32 + m32;
    const short* A = hid2b + m32 * 68 + kh * 8;
    const short* B = wsb + WOFF_FSW2 + n * 16 + kh * 8;
#pragma unroll
    for (int k0 = 0; k0 < 4; ++k0)
      acc = MFMA32(ld8(A + k0 * 16), gld8(B + k0 * 5120), acc);
    const float bias = fsb2[n];
#pragma unroll
    for (int r = 0; r < 16; ++r) {
      int row = (r & 3) + 8 * (r >> 2) + 4 * kh;
      float fsv = acc[r] + bias;
      wb[row * 320 + n] = f2b(fsv * b2f(wb[row * 320 + n]));
    }
  }
  __syncthreads();

  // ---- P4: TP -> f0b (scalars+norms), pvb (vectors) ----
  for (int i = 0; i < 8; ++i) {
    int e = wv * 8 + i;
    int eg = e0 + e; if (eg >= E) eg = E - 1;
    const int dst = eidx[eg], src = eidx[E + eg];
    const float* hs = h + (size_t)src * 256;
    const float* hd = h + (size_t)dst * 256;
    const int u = ln;
    const float w0 = b2f(wb[e * 320 + u]);
    const float w1 = b2f(wb[e * 320 + u + 64]);
    const float w2 = b2f(wb[e * 320 + u + 128]);
    const float w3 = b2f(wb[e * 320 + u + 192]);
    const float w4 = b2f(wb[e * 320 + u + 256]);
    const float xs = hs[u], ys = hd[u];
    const float xv0 = hs[64 + 3 * u], xv1 = hs[64 + 3 * u + 1], xv2 = hs[64 + 3 * u + 2];
    const float yv0 = hd[64 + 3 * u], yv1 = hd[64 + 3 * u + 1], yv2 = hd[64 + 3 * u + 2];
    const float ipv = xv0 * yv0 + xv1 * yv1 + xv2 * yv2;
    const float cr0 = xv1 * yv2 - xv2 * yv1;
    const float cr1 = xv2 * yv0 - xv0 * yv2;
    const float cr2 = xv0 * yv1 - xv1 * yv0;
    const float ps = C0c * (w0 * xs * ys + w3 * ipv * iS3);
    const float k011 = C1c * iS3 * w1 * xs;
    const float k101 = C1c * iS3 * w2 * ys;
    const float k111 = C1c * iS6 * w4;
    const float pv0 = k011 * yv0 + k101 * xv0 + k111 * cr0;
    const float pv1 = k011 * yv1 + k101 * xv1 + k111 * cr1;
    const float pv2 = k011 * yv2 + k101 * xv2 + k111 * cr2;
    f0b[e * 132 + u] = f2b(ps);
    f0b[e * 132 + 64 + u] = f2b(sqrtf(pv0 * pv0 + pv1 * pv1 + pv2 * pv2));
    pvb[e * 192 + 3 * u + 0] = f2b(pv0);
    pvb[e * 192 + 3 * u + 1] = f2b(pv1);
    pvb[e * 192 + 3 * u + 2] = f2b(pv2);
  }
  __syncthreads();

  // ---- P5: g1: t = silu(f0 @ gW1 + gb1) ----
  {
    f32x16 acc = {};
    const int n = wv * 32 + m32;
    const short* A = f0b + m32 * 132 + kh * 8;
    const short* B = wsb + WOFF_GW1 + n * 16 + kh * 8;
#pragma unroll
    for (int k0 = 0; k0 < 8; ++k0)
      acc = MFMA32(ld8(A + k0 * 16), gld8(B + k0 * 2048), acc);
    const float bias = gb1[n];
#pragma unroll
    for (int r = 0; r < 16; ++r) {
      int row = (r & 3) + 8 * (r >> 2) + 4 * kh;
      tb[row * 132 + n] = f2b(siluf(acc[r] + bias));
    }
  }
  __syncthreads();

  // ---- P6: g2: g = t @ gW2 + gb2 ; gate -> gated ----
  {
    f32x16 acc = {};
    const int n = wv * 32 + m32;
    const short* A = tb + m32 * 132 + kh * 8;
    const short* B = wsb + WOFF_GW2 + n * 16 + kh * 8;
#pragma unroll
    for (int k0 = 0; k0 < 8; ++k0)
      acc = MFMA32(ld8(A + k0 * 16), gld8(B + k0 * 2048), acc);
    const float bias = gb2[n];
#pragma unroll
    for (int r = 0; r < 16; ++r) {
      int row = (r & 3) + 8 * (r >> 2) + 4 * kh;
      float val = acc[r] + bias;
      if (wv < 2) {
        gated[row * 68 + n] = f2b(val);
      } else {
        int u = n - 64;
        float p0 = b2f(pvb[row * 192 + 3 * u + 0]);
        float p1 = b2f(pvb[row * 192 + 3 * u + 1]);
        float p2 = b2f(pvb[row * 192 + 3 * u + 2]);
        gated[2176 * 1 + row * 68 + u] = f2b(p0 * val);
        gated[2176 * 2 + row * 68 + u] = f2b(p1 * val);
        gated[2176 * 3 + row * 68 + u] = f2b(p2 * val);
      }
    }
  }
  __syncthreads();

  // ---- P7: Wo: out = o3_linear(gated) + npa ----
  {
    const short* A = gated + 2176 * wv + m32 * 68 + kh * 8;
    const int bofs = (wv == 0) ? WOFF_WO0 : WOFF_WO1;
    for (int nt = 0; nt < 2; ++nt) {
      f32x16 acc = {};
      const int n = nt * 32 + m32;
      const short* B = wsb + bofs + n * 16 + kh * 8;
#pragma unroll
      for (int k0 = 0; k0 < 4; ++k0)
        acc = MFMA32(ld8(A + k0 * 16), gld8(B + k0 * 1024), acc);
      const float bias = (wv == 0) ? bo0[n] : 0.f;
      const int off = (wv == 0) ? n : 64 + 3 * n + (wv - 1);
#pragma unroll
      for (int r = 0; r < 16; ++r) {
        int row = (r & 3) + 8 * (r >> 2) + 4 * kh;
        int eg = e0 + row;
        if (eg < E)
          out[(size_t)eg * 256 + off] = acc[r] * 0.125f + bias + npa[(size_t)eg * 256 + off];
      }
    }
  }
}

extern "C" void kernel_launch(void* const* d_in, const int* in_sizes, int n_in,
                              void* d_out, int out_size, void* d_ws, size_t ws_size,
                              hipStream_t stream) {
  const float* node_attr = (const float*)d_in[0];
  const float* edge_attr = (const float*)d_in[1];
  const float* npa  = (const float*)d_in[2];
  const float* Wi0  = (const float*)d_in[3];
  const float* bi0  = (const float*)d_in[4];
  const float* Wi1  = (const float*)d_in[5];
  const float* gpW1 = (const float*)d_in[6];
  const float* gpb1 = (const float*)d_in[7];
  const float* gpW2 = (const float*)d_in[8];
  const float* gpb2 = (const float*)d_in[9];
  const float* Wn0  = (const float*)d_in[10];
  const float* bn0  = (const float*)d_in[11];
  const float* Wn1  = (const float*)d_in[12];
  const float* feW1 = (const float*)d_in[13];
  const float* feW2 = (const float*)d_in[14];
  const float* fsW1 = (const float*)d_in[15];
  const float* fsb1 = (const float*)d_in[16];
  const float* fsW2 = (const float*)d_in[17];
  const float* fsb2 = (const float*)d_in[18];
  const float* gW1  = (const float*)d_in[19];
  const float* gb1  = (const float*)d_in[20];
  const float* gW2  = (const float*)d_in[21];
  const float* gb2  = (const float*)d_in[22];
  const float* Wo0  = (const float*)d_in[23];
  const float* bo0  = (const float*)d_in[24];
  const float* Wo1  = (const float*)d_in[25];
  const int* eidx = (const int*)d_in[26];

  const int N = in_sizes[0] / 256;
  const int E = in_sizes[1] / 32;

  float* na0 = (float*)d_ws;
  float* h = na0 + (size_t)N * 256;
  short* wsb = (short*)(h + (size_t)N * 256);   // fragment-major bf16 weights (~356 KB)

  (void)hipFuncSetAttribute((const void*)edge_kernel,
                            hipFuncAttributeMaxDynamicSharedMemorySize,
                            LDS_BYTES);

  prep_weights<<<96, 256, 0, stream>>>(fsW1, fsW2, feW1, feW2, gW1, gW2, Wo0, Wo1,
                                       Wi0, Wi1, gpW1, gpW2, Wn0, Wn1, wsb);
  node_kernel<<<(N + 31) / 32, 256, 0, stream>>>(node_attr, bi0, gpb1, gpb2, bn0,
                                                 wsb, na0, h, N);
  edge_kernel<<<(E + 31) / 32, 256, LDS_BYTES, stream>>>(
      edge_attr, npa, fsb1, fsb2, gb1, gb2, bo0, eidx, na0, h, wsb, (float*)d_out, E);
}

// Round 4
// 437.772 us; speedup vs baseline: 2.2812x; 1.1486x over previous
//
#include <hip/hip_runtime.h>
#include <hip/hip_bf16.h>
#include <math.h>

// Round 8: edge-kernel latency attack (node/prep unchanged from round 7).
//  - h-row gathers for the TP phase are register-prefetched at P0 (latency hides
//    under P1-P3 compute instead of being exposed at the P4 phase entry).
//  - P2 (fe2) and P3 (fs2) are fused: identical (row,n) lane ownership means the
//    fe value is produced by the same lane that consumes it -> one barrier and one
//    LDS round-trip removed.
//  - npa rows for the epilogue are register-prefetched at P6 start.

static __device__ __forceinline__ float siluf(float x) { return x / (1.f + __expf(-x)); }
static __device__ __forceinline__ float sspf(float x) {
  return fmaxf(x, 0.f) + log1pf(__expf(-fabsf(x))) - 0.6931471805599453f;
}
static __device__ __forceinline__ short f2b(float x) {
  __hip_bfloat16 b = __float2bfloat16(x);
  short s; __builtin_memcpy(&s, &b, 2); return s;
}
static __device__ __forceinline__ float b2f(short s) {
  unsigned int u = ((unsigned int)(unsigned short)s) << 16;
  float f; __builtin_memcpy(&f, &u, 4); return f;
}

typedef __attribute__((ext_vector_type(4))) short short4v;
typedef __attribute__((ext_vector_type(8))) short short8v;
typedef __attribute__((ext_vector_type(16))) float f32x16;

// LDS A-fragment load: two ds_read_b64 (strides ≡ 4 mod 8 elems => 8B-aligned)
static __device__ __forceinline__ short8v ld8(const short* p) {
  const short4v* q = (const short4v*)p;
  short4v a = q[0], b = q[1];
  short8v r;
  r[0] = a[0]; r[1] = a[1]; r[2] = a[2]; r[3] = a[3];
  r[4] = b[0]; r[5] = b[1]; r[6] = b[2]; r[7] = b[3];
  return r;
}

// Global B-fragment load: single global_load_dwordx4 (fragment-major layout =>
// a wave reads one contiguous 1KB chunk).
static __device__ __forceinline__ short8v gld8(const short* __restrict__ p) {
  return *reinterpret_cast<const short8v*>(p);
}

// hi/lo split store (to LDS)
static __device__ __forceinline__ void sp2(short* hp, short* lp, float x) {
  short hh = f2b(x); *hp = hh; *lp = f2b(x - b2f(hh));
}

// ---- fragment-major bf16 weight table (elem offsets) ----
// layout: elem = ((k0*Ntot + n)*2 + kh)*8 + j ; value = W[k0*16 + kh*8 + j][n]
#define WOFF_FSW1 0        // Ntot=64,  K=192: 12288
#define WOFF_FSW2 12288    // Ntot=320, K=64:  20480
#define WOFF_FEW1 32768    // Ntot=32,  K=32:  1024
#define WOFF_FEW2 33792    // Ntot=320, K=16:  5120
#define WOFF_GW1  38912    // Ntot=128, K=128: 16384
#define WOFF_GW2  55296    // 16384
#define WOFF_WO0  71680    // Ntot=64,  K=64:  4096
#define WOFF_WO1  75776    // 4096
// node (hi table then lo table, each fragment-major):
#define NOFF_WI0  79872    // 4096 x2
#define NOFF_WI1  88064    // 4096 x2
#define NOFF_GP1  96256    // 16384 x2
#define NOFF_GP2  129024   // 16384 x2
#define NOFF_WN0  161792   // 4096 x2
#define NOFF_WN1  169984   // 4096 x2
#define W_ALL     178176

__global__ __launch_bounds__(256) void prep_weights(
    const float* __restrict__ fsW1, const float* __restrict__ fsW2,
    const float* __restrict__ feW1, const float* __restrict__ feW2,
    const float* __restrict__ gW1, const float* __restrict__ gW2,
    const float* __restrict__ Wo0, const float* __restrict__ Wo1,
    const float* __restrict__ Wi0, const float* __restrict__ Wi1,
    const float* __restrict__ gpW1, const float* __restrict__ gpW2,
    const float* __restrict__ Wn0, const float* __restrict__ Wn1,
    short* __restrict__ wsb)
{
  const int gt = blockIdx.x * blockDim.x + threadIdx.x;
  const int gs = gridDim.x * blockDim.x;
  for (int i = gt; i < 12288; i += gs) { int k = (i >> 10) * 16 + (i & 15), n = (i >> 4) & 63;  wsb[WOFF_FSW1 + i] = f2b(fsW1[k * 64 + n]); }
  for (int i = gt; i < 20480; i += gs) { int k = (i / 5120) * 16 + (i & 15), n = (i >> 4) % 320; wsb[WOFF_FSW2 + i] = f2b(fsW2[k * 320 + n]); }
  for (int i = gt; i < 1024; i += gs)  { int k = (i >> 9) * 16 + (i & 15),  n = (i >> 4) & 31;  wsb[WOFF_FEW1 + i] = (n < 8) ? f2b(feW1[k * 8 + n]) : 0; }
  for (int i = gt; i < 5120; i += gs)  { int k = i & 15,                    n = (i >> 4) % 320; wsb[WOFF_FEW2 + i] = (k < 8) ? f2b(feW2[k * 320 + n]) : 0; }
  for (int i = gt; i < 16384; i += gs) { int k = (i >> 11) * 16 + (i & 15), n = (i >> 4) & 127; wsb[WOFF_GW1 + i] = f2b(gW1[k * 128 + n]); }
  for (int i = gt; i < 16384; i += gs) { int k = (i >> 11) * 16 + (i & 15), n = (i >> 4) & 127; wsb[WOFF_GW2 + i] = f2b(gW2[k * 128 + n]); }
  for (int i = gt; i < 4096; i += gs)  { int k = (i >> 10) * 16 + (i & 15), n = (i >> 4) & 63;  wsb[WOFF_WO0 + i] = f2b(Wo0[k * 64 + n]); }
  for (int i = gt; i < 4096; i += gs)  { int k = (i >> 10) * 16 + (i & 15), n = (i >> 4) & 63;  wsb[WOFF_WO1 + i] = f2b(Wo1[k * 64 + n]); }
  for (int i = gt; i < 4096; i += gs)  { int k = (i >> 10) * 16 + (i & 15), n = (i >> 4) & 63;  float w = Wi0[k * 64 + n];  short hh = f2b(w); wsb[NOFF_WI0 + i] = hh; wsb[NOFF_WI0 + 4096 + i] = f2b(w - b2f(hh)); }
  for (int i = gt; i < 4096; i += gs)  { int k = (i >> 10) * 16 + (i & 15), n = (i >> 4) & 63;  float w = Wi1[k * 64 + n];  short hh = f2b(w); wsb[NOFF_WI1 + i] = hh; wsb[NOFF_WI1 + 4096 + i] = f2b(w - b2f(hh)); }
  for (int i = gt; i < 16384; i += gs) { int k = (i >> 11) * 16 + (i & 15), n = (i >> 4) & 127; float w = gpW1[k * 128 + n]; short hh = f2b(w); wsb[NOFF_GP1 + i] = hh; wsb[NOFF_GP1 + 16384 + i] = f2b(w - b2f(hh)); }
  for (int i = gt; i < 16384; i += gs) { int k = (i >> 11) * 16 + (i & 15), n = (i >> 4) & 127; float w = gpW2[k * 128 + n]; short hh = f2b(w); wsb[NOFF_GP2 + i] = hh; wsb[NOFF_GP2 + 16384 + i] = f2b(w - b2f(hh)); }
  for (int i = gt; i < 4096; i += gs)  { int k = (i >> 10) * 16 + (i & 15), n = (i >> 4) & 63;  float w = Wn0[k * 64 + n];  short hh = f2b(w); wsb[NOFF_WN0 + i] = hh; wsb[NOFF_WN0 + 4096 + i] = f2b(w - b2f(hh)); }
  for (int i = gt; i < 4096; i += gs)  { int k = (i >> 10) * 16 + (i & 15), n = (i >> 4) & 63;  float w = Wn1[k * 64 + n];  short hh = f2b(w); wsb[NOFF_WN1 + i] = hh; wsb[NOFF_WN1 + 4096 + i] = f2b(w - b2f(hh)); }
}

#define MFMA32(a, b, c) __builtin_amdgcn_mfma_f32_32x32x16_bf16(a, b, c, 0, 0, 0)

// hi/lo K-step: 3 MFMAs, ~fp32-accurate
#define MFMA_HL(ah, al, bh, bl, acc) \
  do { acc = MFMA32((al), (bh), acc); acc = MFMA32((ah), (bl), acc); acc = MFMA32((ah), (bh), acc); } while (0)

// ---- node kernel (unchanged from round 7) ----
#define XS_H 0
#define V0H  4352
#define F0H  17408
#define F0L  21632
#define TBH  0
#define TBL  4224
#define GVH  8704
#define GSH  21760
#define GSL  23936
#define NODE_LDS_SHORTS 26112   // 52224 B => 3 blocks/CU (LDS-limited)

__global__ __launch_bounds__(256, 2) void node_kernel(
    const float* __restrict__ na,
    const float* __restrict__ bi0, const float* __restrict__ gpb1,
    const float* __restrict__ gpb2, const float* __restrict__ bn0,
    const short* __restrict__ wsb,
    float* __restrict__ na0, float* __restrict__ h, int N)
{
  __shared__ __align__(16) short smem[NODE_LDS_SHORTS];
  const int tid = threadIdx.x;
  const int wv = tid >> 6, ln = tid & 63;
  const int m32 = ln & 31, kh = ln >> 5;
  const int nb0 = blockIdx.x * 32;

  for (int i = 0; i < 8; ++i) {
    const int e = wv * 8 + i;
    int ng = nb0 + e; if (ng >= N) ng = N - 1;
    const float* xp = na + (size_t)ng * 256;
    const int u = ln;
    const float xs = xp[u];
    const float v0 = xp[64 + 3 * u], v1 = xp[64 + 3 * u + 1], v2 = xp[64 + 3 * u + 2];
    const float nr = sqrtf(v0 * v0 + v1 * v1 + v2 * v2);
    sp2(smem + XS_H + e * 68 + u,        smem + XS_H + 2176 + e * 68 + u, xs);
    sp2(smem + V0H + 0 * 4352 + e * 68 + u, smem + V0H + 0 * 4352 + 2176 + e * 68 + u, v0);
    sp2(smem + V0H + 1 * 4352 + e * 68 + u, smem + V0H + 1 * 4352 + 2176 + e * 68 + u, v1);
    sp2(smem + V0H + 2 * 4352 + e * 68 + u, smem + V0H + 2 * 4352 + 2176 + e * 68 + u, v2);
    sp2(smem + F0H + e * 132 + u,        smem + F0L + e * 132 + u, xs);
    sp2(smem + F0H + e * 132 + 64 + u,   smem + F0L + e * 132 + 64 + u, nr);
  }
  __syncthreads();

  {
    const int g = wv;
    const short* Ah = smem + (g == 0 ? XS_H : V0H + (g - 1) * 4352) + m32 * 68 + kh * 8;
    const short* Al = Ah + 2176;
    const int bofs = (g == 0) ? NOFF_WI0 : NOFF_WI1;
    for (int nt = 0; nt < 2; ++nt) {
      f32x16 acc = {};
      const int n = nt * 32 + m32;
      const short* Bh = wsb + bofs + n * 16 + kh * 8;
      const short* Bl = Bh + 4096;
#pragma unroll 2
      for (int k0 = 0; k0 < 4; ++k0) {
        short8v ah = ld8(Ah + k0 * 16), al = ld8(Al + k0 * 16);
        short8v bh = gld8(Bh + k0 * 1024), bl = gld8(Bl + k0 * 1024);
        MFMA_HL(ah, al, bh, bl, acc);
      }
      const float bias = (g == 0) ? bi0[n] : 0.f;
      const int off = (g == 0) ? n : 64 + 3 * n + (g - 1);
#pragma unroll
      for (int r = 0; r < 16; ++r) {
        int row = (r & 3) + 8 * (r >> 2) + 4 * kh;
        int ng = nb0 + row;
        if (ng < N) na0[(size_t)ng * 256 + off] = acc[r] * 0.125f + bias;
      }
    }
  }
  __syncthreads();

  {
    f32x16 acc = {};
    const int n = wv * 32 + m32;
    const short* Ah = smem + F0H + m32 * 132 + kh * 8;
    const short* Al = smem + F0L + m32 * 132 + kh * 8;
    const short* Bh = wsb + NOFF_GP1 + n * 16 + kh * 8;
    const short* Bl = Bh + 16384;
#pragma unroll 2
    for (int k0 = 0; k0 < 8; ++k0) {
      short8v ah = ld8(Ah + k0 * 16), al = ld8(Al + k0 * 16);
      short8v bh = gld8(Bh + k0 * 2048), bl = gld8(Bl + k0 * 2048);
      MFMA_HL(ah, al, bh, bl, acc);
    }
    const float bias = gpb1[n];
#pragma unroll
    for (int r = 0; r < 16; ++r) {
      int row = (r & 3) + 8 * (r >> 2) + 4 * kh;
      float t = siluf(acc[r] + bias);
      sp2(smem + TBH + row * 132 + n, smem + TBL + row * 132 + n, t);
    }
  }
  __syncthreads();

  {
    f32x16 acc = {};
    const int n = wv * 32 + m32;
    const short* Ah = smem + TBH + m32 * 132 + kh * 8;
    const short* Al = smem + TBL + m32 * 132 + kh * 8;
    const short* Bh = wsb + NOFF_GP2 + n * 16 + kh * 8;
    const short* Bl = Bh + 16384;
#pragma unroll 2
    for (int k0 = 0; k0 < 8; ++k0) {
      short8v ah = ld8(Ah + k0 * 16), al = ld8(Al + k0 * 16);
      short8v bh = gld8(Bh + k0 * 2048), bl = gld8(Bl + k0 * 2048);
      MFMA_HL(ah, al, bh, bl, acc);
    }
    const float bias = gpb2[n];
#pragma unroll
    for (int r = 0; r < 16; ++r) {
      int row = (r & 3) + 8 * (r >> 2) + 4 * kh;
      float val = acc[r] + bias;
      if (wv < 2) {
        sp2(smem + GSH + row * 68 + n, smem + GSL + row * 68 + n, val);
      } else {
        const int u = n - 64;
        int ng = nb0 + row; if (ng >= N) ng = N - 1;
        const float* vp = na + (size_t)ng * 256 + 64 + 3 * u;
#pragma unroll
        for (int c = 0; c < 3; ++c) {
          float pv = vp[c] * val;
          sp2(smem + GVH + c * 4352 + row * 68 + u,
              smem + GVH + c * 4352 + 2176 + row * 68 + u, pv);
        }
      }
    }
  }
  __syncthreads();

  {
    const int g = wv;
    const short* Ah = smem + (g == 0 ? GSH : GVH + (g - 1) * 4352) + m32 * 68 + kh * 8;
    const short* Al = Ah + 2176;
    const int bofs = (g == 0) ? NOFF_WN0 : NOFF_WN1;
    for (int nt = 0; nt < 2; ++nt) {
      f32x16 acc = {};
      const int n = nt * 32 + m32;
      const short* Bh = wsb + bofs + n * 16 + kh * 8;
      const short* Bl = Bh + 4096;
#pragma unroll 2
      for (int k0 = 0; k0 < 4; ++k0) {
        short8v ah = ld8(Ah + k0 * 16), al = ld8(Al + k0 * 16);
        short8v bh = gld8(Bh + k0 * 1024), bl = gld8(Bl + k0 * 1024);
        MFMA_HL(ah, al, bh, bl, acc);
      }
      const float bias = (g == 0) ? bn0[n] : 0.f;
      const int off = (g == 0) ? n : 64 + 3 * n + (g - 1);
#pragma unroll
      for (int r = 0; r < 16; ++r) {
        int row = (r & 3) + 8 * (r >> 2) + 4 * kh;
        int ng = nb0 + row;
        if (ng < N) h[(size_t)ng * 256 + off] = acc[r] * 0.125f + bias;
      }
    }
  }
}

// ---- edge kernel LDS arena (one barrier fewer; same aliasing) ----
// P0 build | P1 fs1+fe1 | P2' fe2*fs2 | P4 TP | P5 g1 | P6 g2+gate | P7 Wo
#define A_HIDE  0
#define A_HID2  640
#define A_S0    2816
#define A_EA    9088
#define A_WB    2816
#define A_F0    13056
#define A_PV    17280
#define A_TB    2816
#define A_GATED 7040
#define ACT_TOTAL 23424
#define LDS_BYTES (ACT_TOTAL * 2)   // 46848 B => 3 blocks/CU

__global__ __launch_bounds__(256, 3) void edge_kernel(
    const float* __restrict__ ea,
    const float* __restrict__ npa,
    const float* __restrict__ fsb1, const float* __restrict__ fsb2,
    const float* __restrict__ gb1, const float* __restrict__ gb2,
    const float* __restrict__ bo0,
    const int* __restrict__ eidx,
    const float* __restrict__ na0, const float* __restrict__ h,
    const short* __restrict__ wsb,
    float* __restrict__ out, int E)
{
  extern __shared__ __align__(16) short smem[];
  short* hidEb  = smem + A_HIDE;
  short* hid2b  = smem + A_HID2;
  short* s0b    = smem + A_S0;
  short* earowb = smem + A_EA;
  short* wb     = smem + A_WB;
  short* f0b    = smem + A_F0;
  short* pvb    = smem + A_PV;
  short* tb     = smem + A_TB;
  short* gated  = smem + A_GATED;

  const int tid = threadIdx.x;
  const int wv = tid >> 6, ln = tid & 63;
  const int m32 = ln & 31, kh = ln >> 5;
  const int e0 = blockIdx.x * 32;

  const float C0c = 0.4472135954999579f;   // sqrt(1/5)
  const float C1c = 0.7745966692414834f;   // sqrt(3/5)
  const float iS3 = 0.5773502691896258f;
  const float iS6 = 0.40824829046386307f;
  const float isq32 = 0.17677669529663687f;
  const float isq8 = 0.35355339059327373f;

  // ---- entry: edge indices for this wave's 8 edges ----
  int dstI[8], srcI[8];
#pragma unroll
  for (int i = 0; i < 8; ++i) {
    int eg = e0 + wv * 8 + i; if (eg >= E) eg = E - 1;
    dstI[i] = eidx[eg]; srcI[i] = eidx[E + eg];
  }

  // ---- prefetch h rows for P4 (latency hides under P0-P2') ----
  float hs_s[8], hd_s[8];
  float hs_v0[8], hs_v1[8], hs_v2[8], hd_v0[8], hd_v1[8], hd_v2[8];
#pragma unroll
  for (int i = 0; i < 8; ++i) {
    const float* hs = h + (size_t)srcI[i] * 256;
    const float* hd = h + (size_t)dstI[i] * 256;
    hs_s[i] = hs[ln];
    hd_s[i] = hd[ln];
    hs_v0[i] = hs[64 + 3 * ln];
    hs_v1[i] = hs[64 + 3 * ln + 1];
    hs_v2[i] = hs[64 + 3 * ln + 2];
    hd_v0[i] = hd[64 + 3 * ln];
    hd_v1[i] = hd[64 + 3 * ln + 1];
    hd_v2[i] = hd[64 + 3 * ln + 2];
  }

  // ---- P0: build earow, zero hidE, build s0 ----
  for (int i = tid; i < 32 * 32; i += 256) {
    int e = i >> 5, k = i & 31;
    int eg = e0 + e; if (eg >= E) eg = E - 1;
    earowb[e * 36 + k] = f2b(ea[(size_t)eg * 32 + k]);
  }
  for (int i = tid; i < 640; i += 256) hidEb[i] = 0;
#pragma unroll
  for (int i = 0; i < 8; ++i) {
    const int e = wv * 8 + i;
    const float* nd = na0 + (size_t)dstI[i] * 256;
    const float* ns = na0 + (size_t)srcI[i] * 256;
    const int u = ln;
    float ip = nd[64 + 3 * u] * ns[64 + 3 * u] + nd[64 + 3 * u + 1] * ns[64 + 3 * u + 1]
             + nd[64 + 3 * u + 2] * ns[64 + 3 * u + 2];
    s0b[e * 196 + u] = f2b(nd[u]);
    s0b[e * 196 + 64 + u] = f2b(ns[u]);
    s0b[e * 196 + 128 + u] = f2b(ip * (1.f / 3.f));
  }
  __syncthreads();

  // ---- P1: fs1 (waves 0,1): hid2 = silu(s0 @ fsW1 + fsb1); fe1 (wave 2) ----
  if (wv < 2) {
    f32x16 acc = {};
    const int n = wv * 32 + m32;
    const short* A = s0b + m32 * 196 + kh * 8;
    const short* B = wsb + WOFF_FSW1 + n * 16 + kh * 8;
#pragma unroll
    for (int k0 = 0; k0 < 12; ++k0)
      acc = MFMA32(ld8(A + k0 * 16), gld8(B + k0 * 1024), acc);
    const float bias = fsb1[n];
#pragma unroll
    for (int r = 0; r < 16; ++r) {
      int row = (r & 3) + 8 * (r >> 2) + 4 * kh;
      hid2b[row * 68 + n] = f2b(siluf(acc[r] + bias));
    }
  } else if (wv == 2) {
    f32x16 acc = {};
    const short* A = earowb + m32 * 36 + kh * 8;
    const short* B = wsb + WOFF_FEW1 + m32 * 16 + kh * 8;
#pragma unroll
    for (int k0 = 0; k0 < 2; ++k0)
      acc = MFMA32(ld8(A + k0 * 16), gld8(B + k0 * 512), acc);
    if (m32 < 8) {
#pragma unroll
      for (int r = 0; r < 16; ++r) {
        int row = (r & 3) + 8 * (r >> 2) + 4 * kh;
        hidEb[row * 20 + m32] = f2b(sspf(acc[r] * isq32));
      }
    }
  }
  __syncthreads();

  // ---- P2': fused fe2 + fs2 -> w = (hid2@fsW2 + fsb2) * (hidE@feW2)/sqrt(8) ----
  // Same (row,n) lane ownership in both GEMMs => no LDS round-trip, no barrier.
  for (int nt = wv; nt < 10; nt += 4) {
    const int n = nt * 32 + m32;
    f32x16 aF = {};
    aF = MFMA32(ld8(hidEb + m32 * 20 + kh * 8), gld8(wsb + WOFF_FEW2 + n * 16 + kh * 8), aF);
    f32x16 aS = {};
    const short* A = hid2b + m32 * 68 + kh * 8;
    const short* B = wsb + WOFF_FSW2 + n * 16 + kh * 8;
#pragma unroll
    for (int k0 = 0; k0 < 4; ++k0)
      aS = MFMA32(ld8(A + k0 * 16), gld8(B + k0 * 5120), aS);
    const float bias = fsb2[n];
#pragma unroll
    for (int r = 0; r < 16; ++r) {
      int row = (r & 3) + 8 * (r >> 2) + 4 * kh;
      wb[row * 320 + n] = f2b((aS[r] + bias) * (aF[r] * isq8));
    }
  }
  __syncthreads();

  // ---- P4: TP (h operands from prefetched registers) -> f0b, pvb ----
#pragma unroll
  for (int i = 0; i < 8; ++i) {
    const int e = wv * 8 + i;
    const int u = ln;
    const float w0 = b2f(wb[e * 320 + u]);
    const float w1 = b2f(wb[e * 320 + u + 64]);
    const float w2 = b2f(wb[e * 320 + u + 128]);
    const float w3 = b2f(wb[e * 320 + u + 192]);
    const float w4 = b2f(wb[e * 320 + u + 256]);
    const float xs = hs_s[i], ys = hd_s[i];
    const float xv0 = hs_v0[i], xv1 = hs_v1[i], xv2 = hs_v2[i];
    const float yv0 = hd_v0[i], yv1 = hd_v1[i], yv2 = hd_v2[i];
    const float ipv = xv0 * yv0 + xv1 * yv1 + xv2 * yv2;
    const float cr0 = xv1 * yv2 - xv2 * yv1;
    const float cr1 = xv2 * yv0 - xv0 * yv2;
    const float cr2 = xv0 * yv1 - xv1 * yv0;
    const float ps = C0c * (w0 * xs * ys + w3 * ipv * iS3);
    const float k011 = C1c * iS3 * w1 * xs;
    const float k101 = C1c * iS3 * w2 * ys;
    const float k111 = C1c * iS6 * w4;
    const float pv0 = k011 * yv0 + k101 * xv0 + k111 * cr0;
    const float pv1 = k011 * yv1 + k101 * xv1 + k111 * cr1;
    const float pv2 = k011 * yv2 + k101 * xv2 + k111 * cr2;
    f0b[e * 132 + u] = f2b(ps);
    f0b[e * 132 + 64 + u] = f2b(sqrtf(pv0 * pv0 + pv1 * pv1 + pv2 * pv2));
    pvb[e * 192 + 3 * u + 0] = f2b(pv0);
    pvb[e * 192 + 3 * u + 1] = f2b(pv1);
    pvb[e * 192 + 3 * u + 2] = f2b(pv2);
  }
  __syncthreads();

  // ---- P5: g1: t = silu(f0 @ gW1 + gb1) ----
  {
    f32x16 acc = {};
    const int n = wv * 32 + m32;
    const short* A = f0b + m32 * 132 + kh * 8;
    const short* B = wsb + WOFF_GW1 + n * 16 + kh * 8;
#pragma unroll
    for (int k0 = 0; k0 < 8; ++k0)
      acc = MFMA32(ld8(A + k0 * 16), gld8(B + k0 * 2048), acc);
    const float bias = gb1[n];
#pragma unroll
    for (int r = 0; r < 16; ++r) {
      int row = (r & 3) + 8 * (r >> 2) + 4 * kh;
      tb[row * 132 + n] = f2b(siluf(acc[r] + bias));
    }
  }
  __syncthreads();

  // ---- P6: prefetch npa (for P7), then g2: g = t @ gW2 + gb2 ; gate -> gated ----
  float npv[2][16];
  {
#pragma unroll
    for (int nt = 0; nt < 2; ++nt) {
      const int n = nt * 32 + m32;
      const int off = (wv == 0) ? n : 64 + 3 * n + (wv - 1);
#pragma unroll
      for (int r = 0; r < 16; ++r) {
        int row = (r & 3) + 8 * (r >> 2) + 4 * kh;
        int eg = e0 + row;
        npv[nt][r] = (eg < E) ? npa[(size_t)eg * 256 + off] : 0.f;
      }
    }
  }
  {
    f32x16 acc = {};
    const int n = wv * 32 + m32;
    const short* A = tb + m32 * 132 + kh * 8;
    const short* B = wsb + WOFF_GW2 + n * 16 + kh * 8;
#pragma unroll
    for (int k0 = 0; k0 < 8; ++k0)
      acc = MFMA32(ld8(A + k0 * 16), gld8(B + k0 * 2048), acc);
    const float bias = gb2[n];
#pragma unroll
    for (int r = 0; r < 16; ++r) {
      int row = (r & 3) + 8 * (r >> 2) + 4 * kh;
      float val = acc[r] + bias;
      if (wv < 2) {
        gated[row * 68 + n] = f2b(val);
      } else {
        int u = n - 64;
        float p0 = b2f(pvb[row * 192 + 3 * u + 0]);
        float p1 = b2f(pvb[row * 192 + 3 * u + 1]);
        float p2 = b2f(pvb[row * 192 + 3 * u + 2]);
        gated[2176 * 1 + row * 68 + u] = f2b(p0 * val);
        gated[2176 * 2 + row * 68 + u] = f2b(p1 * val);
        gated[2176 * 3 + row * 68 + u] = f2b(p2 * val);
      }
    }
  }
  __syncthreads();

  // ---- P7: Wo: out = o3_linear(gated) + npa(prefetched) ----
  {
    const short* A = gated + 2176 * wv + m32 * 68 + kh * 8;
    const int bofs = (wv == 0) ? WOFF_WO0 : WOFF_WO1;
#pragma unroll
    for (int nt = 0; nt < 2; ++nt) {
      f32x16 acc = {};
      const int n = nt * 32 + m32;
      const short* B = wsb + bofs + n * 16 + kh * 8;
#pragma unroll
      for (int k0 = 0; k0 < 4; ++k0)
        acc = MFMA32(ld8(A + k0 * 16), gld8(B + k0 * 1024), acc);
      const float bias = (wv == 0) ? bo0[n] : 0.f;
      const int off = (wv == 0) ? n : 64 + 3 * n + (wv - 1);
#pragma unroll
      for (int r = 0; r < 16; ++r) {
        int row = (r & 3) + 8 * (r >> 2) + 4 * kh;
        int eg = e0 + row;
        if (eg < E)
          out[(size_t)eg * 256 + off] = acc[r] * 0.125f + bias + npv[nt][r];
      }
    }
  }
}

extern "C" void kernel_launch(void* const* d_in, const int* in_sizes, int n_in,
                              void* d_out, int out_size, void* d_ws, size_t ws_size,
                              hipStream_t stream) {
  const float* node_attr = (const float*)d_in[0];
  const float* edge_attr = (const float*)d_in[1];
  const float* npa  = (const float*)d_in[2];
  const float* Wi0  = (const float*)d_in[3];
  const float* bi0  = (const float*)d_in[4];
  const float* Wi1  = (const float*)d_in[5];
  const float* gpW1 = (const float*)d_in[6];
  const float* gpb1 = (const float*)d_in[7];
  const float* gpW2 = (const float*)d_in[8];
  const float* gpb2 = (const float*)d_in[9];
  const float* Wn0  = (const float*)d_in[10];
  const float* bn0  = (const float*)d_in[11];
  const float* Wn1  = (const float*)d_in[12];
  const float* feW1 = (const float*)d_in[13];
  const float* feW2 = (const float*)d_in[14];
  const float* fsW1 = (const float*)d_in[15];
  const float* fsb1 = (const float*)d_in[16];
  const float* fsW2 = (const float*)d_in[17];
  const float* fsb2 = (const float*)d_in[18];
  const float* gW1  = (const float*)d_in[19];
  const float* gb1  = (const float*)d_in[20];
  const float* gW2  = (const float*)d_in[21];
  const float* gb2  = (const float*)d_in[22];
  const float* Wo0  = (const float*)d_in[23];
  const float* bo0  = (const float*)d_in[24];
  const float* Wo1  = (const float*)d_in[25];
  const int* eidx = (const int*)d_in[26];

  const int N = in_sizes[0] / 256;
  const int E = in_sizes[1] / 32;

  float* na0 = (float*)d_ws;
  float* h = na0 + (size_t)N * 256;
  short* wsb = (short*)(h + (size_t)N * 256);   // fragment-major bf16 weights (~356 KB)

  (void)hipFuncSetAttribute((const void*)edge_kernel,
                            hipFuncAttributeMaxDynamicSharedMemorySize,
                            LDS_BYTES);

  prep_weights<<<96, 256, 0, stream>>>(fsW1, fsW2, feW1, feW2, gW1, gW2, Wo0, Wo1,
                                       Wi0, Wi1, gpW1, gpW2, Wn0, Wn1, wsb);
  node_kernel<<<(N + 31) / 32, 256, 0, stream>>>(node_attr, bi0, gpb1, gpb2, bn0,
                                                 wsb, na0, h, N);
  edge_kernel<<<(E + 31) / 32, 256, LDS_BYTES, stream>>>(
      edge_attr, npa, fsb1, fsb2, gb1, gb2, bo0, eidx, na0, h, wsb, (float*)d_out, E);
}